// Round 4
// baseline (1125.094 us; speedup 1.0000x reference)
//
#include <hip/hip_runtime.h>
#include <math.h>

typedef unsigned short u16;
typedef __bf16 bf16x8 __attribute__((ext_vector_type(8)));
typedef float f32x4 __attribute__((ext_vector_type(4)));
typedef unsigned short u16x4 __attribute__((ext_vector_type(4)));
typedef unsigned short u16x8 __attribute__((ext_vector_type(8)));

#define DEV static __device__ __forceinline__

DEV float bf2f(u16 u) { union { unsigned int i; float f; } x; x.i = ((unsigned int)u) << 16; return x.f; }
DEV u16 f2bf(float f) { union { float f; unsigned int i; } x; x.f = f; unsigned int r = x.i + 0x7fffu + ((x.i >> 16) & 1u); return (u16)(r >> 16); }

DEV void load_lds16(const void* g, void* l) {
  __builtin_amdgcn_global_load_lds((__attribute__((address_space(1))) void*)g,
                                   (__attribute__((address_space(3))) void*)l, 16, 0, 0);
}

// ---------------------------------------------------------------------------
// Generic NT GEMM (proven, unchanged): C[m,n]=sum_k A[m,k]*B[n,k], 128x128,
// BK=64, 4 waves, MFMA 16x16x32, XOR swizzle both-sides, T1 XCD swizzle.
// EPI: 0 bf16 | 3 f32 v+aux0[col]+aux1 | 4 bias+gelu bf16 | 5 f32 += | 6 f32
// ---------------------------------------------------------------------------
template<int EPI>
__global__ __launch_bounds__(256, 2)
void gemm_nt(const u16* __restrict__ A, const u16* __restrict__ B, void* __restrict__ Cv,
             const float* __restrict__ aux0, const float* __restrict__ aux1,
             int M, int N, int K, int lda, int ldb, int ldc,
             long sAb, long sAh, long sBb, long sBh, long sCb, long sCh,
             int ksplit, long sKs)
{
  __shared__ __align__(16) unsigned char smem[32768];
  const int tid = threadIdx.x;
  const int bz = blockIdx.z;
  const long ob = bz >> 4, oh = bz & 15;
  const u16* Ab = A + ob * sAb + oh * sAh;
  const u16* Bb = B + ob * sBb + oh * sBh;
  int bx = blockIdx.x, by = blockIdx.y;
  if (ksplit == 1 && gridDim.z == 1) {
    int nwg = gridDim.x * gridDim.y;
    if ((nwg & 7) == 0) {
      int wg = by * gridDim.x + bx;
      int swz = (wg & 7) * (nwg >> 3) + (wg >> 3);
      bx = swz % gridDim.x; by = swz / gridDim.x;
    }
  }
  int mt = by, ks = 0;
  if (ksplit > 1) { ks = blockIdx.y; mt = 0; }
  const long cOff = ob * sCb + oh * sCh + (long)ks * sKs;
  const int m0 = mt * 128, n0 = bx * 128;
  const int kchunk = K / ksplit;
  const int klo = ks * kchunk, khi = klo + kchunk;
  const int wid = tid >> 6, lane = tid & 63;
  const int wr = wid >> 1, wc = wid & 1;
  const int ln15 = lane & 15, lq = lane >> 4;
  const int srow = tid >> 3, sch = tid & 7;

  f32x4 acc[4][4] = {};

  for (int k0 = klo; k0 < khi; k0 += 64) {
#pragma unroll
    for (int i = 0; i < 4; ++i) {
      int r = i * 32 + srow;
      int gr = m0 + r; gr = gr < M ? gr : M - 1;
      const unsigned char* src = (const unsigned char*)(Ab + (size_t)gr * lda + k0) + ((sch ^ (r & 7)) << 4);
      load_lds16(src, smem + r * 128 + (sch << 4));
    }
#pragma unroll
    for (int i = 0; i < 4; ++i) {
      int r = i * 32 + srow;
      int gc = n0 + r; gc = gc < N ? gc : N - 1;
      const unsigned char* src = (const unsigned char*)(Bb + (size_t)gc * ldb + k0) + ((sch ^ (r & 7)) << 4);
      load_lds16(src, smem + 16384 + r * 128 + (sch << 4));
    }
    __syncthreads();
#pragma unroll
    for (int kk = 0; kk < 2; ++kk) {
      bf16x8 af[4], bfv[4];
#pragma unroll
      for (int m = 0; m < 4; ++m) {
        int r = wr * 64 + m * 16 + ln15;
        int kc = kk * 4 + lq;
        af[m] = *(const bf16x8*)(smem + r * 128 + ((kc ^ (r & 7)) << 4));
      }
#pragma unroll
      for (int n = 0; n < 4; ++n) {
        int r = wc * 64 + n * 16 + ln15;
        int kc = kk * 4 + lq;
        bfv[n] = *(const bf16x8*)(smem + 16384 + r * 128 + ((kc ^ (r & 7)) << 4));
      }
#pragma unroll
      for (int m = 0; m < 4; ++m)
#pragma unroll
        for (int n = 0; n < 4; ++n)
          acc[m][n] = __builtin_amdgcn_mfma_f32_16x16x32_bf16(af[m], bfv[n], acc[m][n], 0, 0, 0);
    }
    __syncthreads();
  }

#pragma unroll
  for (int m = 0; m < 4; ++m) {
#pragma unroll
    for (int n = 0; n < 4; ++n) {
      int col = n0 + wc * 64 + n * 16 + ln15;
      if (col >= N) continue;
#pragma unroll
      for (int j = 0; j < 4; ++j) {
        int row = m0 + wr * 64 + m * 16 + lq * 4 + j;
        if (row >= M) continue;
        float v = acc[m][n][j];
        size_t idx = cOff + (size_t)row * ldc + col;
        if (EPI == 0) {
          ((u16*)Cv)[idx] = f2bf(v);
        } else if (EPI == 3) {
          ((float*)Cv)[idx] = v + aux0[col] + aux1[(size_t)row * ldc + col];
        } else if (EPI == 4) {
          float g = v + aux0[col];
          float o = 0.5f * g * (1.f + erff(g * 0.70710678118f));
          ((u16*)Cv)[idx] = f2bf(o);
        } else if (EPI == 5) {
          ((float*)Cv)[idx] += v;
        } else if (EPI == 6) {
          ((float*)Cv)[idx] = v;
        }
      }
    }
  }
}

// ---------------------------------------------------------------------------
// fused_kv v2: grid (16 chunks, 64 bh), 256 thr, 3 blocks/CU target.
// proj A-frags in registers (direct per-lane global loads, L2-resident).
// Per 64-n tile: stage k (global_load_lds) + v reg-transposed into LDS;
// kfT=elu(projT@k^T)+1 -> kfS; ksum += rowsums; kv[f,d] += kfT@vT^T.
// Writes f32 partials (kvpart = d_out, 16 per bh) + ksum partials.
// ---------------------------------------------------------------------------
__global__ __launch_bounds__(256, 3)
void fused_kv(const u16* __restrict__ qkv, const u16* __restrict__ projT,
              float* __restrict__ kvpart, float* __restrict__ ksumpart)
{
  __shared__ __align__(16) unsigned char ktS[8192];
  __shared__ __align__(16) unsigned char vtS[8192];
  __shared__ __align__(16) unsigned char kfS[32768];
  const int tid = threadIdx.x;
  const int bh = blockIdx.y, chunk = blockIdx.x;
  const int b = bh >> 4, h = bh & 15;
  const int wid = tid >> 6, lane = tid & 63;
  const int ln15 = lane & 15, lq = lane >> 4;

  // proj fragments: wave owns f in [wid*64, +64): pf[m][kk]
  bf16x8 pf[4][2];
#pragma unroll
  for (int m = 0; m < 4; ++m)
#pragma unroll
    for (int kk = 0; kk < 2; ++kk) {
      int f = wid * 64 + m * 16 + ln15;
      pf[m][kk] = *(const bf16x8*)(projT + (size_t)h * 16384 + (size_t)f * 64 + (kk * 4 + lq) * 8);
    }

  float ksum_r = 0.f;
  f32x4 acc2[4][4] = {};

  for (int t = 0; t < 4; ++t) {
    int n0 = chunk * 256 + t * 64;
    // stage k tile [64n][64d] via global_load_lds (source-XOR swizzle)
    const u16* kg = qkv + ((size_t)b * 4096 + n0) * 3072 + 1024 + h * 64;
#pragma unroll
    for (int i = 0; i < 2; ++i) {
      int c = i * 256 + tid; int r = c >> 3, ch = c & 7;
      load_lds16((const unsigned char*)(kg + (size_t)r * 3072) + ((ch ^ (r & 7)) << 4),
                 ktS + r * 128 + ch * 16);
    }
    // stage v transposed: thread loads v[n][dblk..dblk+16), writes u16 scatter
    {
      int nloc = tid >> 2, dblk = (tid & 3) * 16;
      const u16* vg = qkv + ((size_t)b * 4096 + n0 + nloc) * 3072 + 2048 + h * 64 + dblk;
      u16x8 v0 = *(const u16x8*)vg;
      u16x8 v1 = *(const u16x8*)(vg + 8);
      int cn = nloc >> 3, wb = (nloc & 7) * 2;
#pragma unroll
      for (int j = 0; j < 8; ++j) {
        int d = dblk + j;
        *(u16*)(vtS + d * 128 + ((cn ^ (d & 7)) << 4) + wb) = v0[j];
      }
#pragma unroll
      for (int j = 0; j < 8; ++j) {
        int d = dblk + 8 + j;
        *(u16*)(vtS + d * 128 + ((cn ^ (d & 7)) << 4) + wb) = v1[j];
      }
    }
    __syncthreads();

    // MFMA1 (m-outer to bound VGPR): kf[f, nloc] then elu+1 -> kfS
    bf16x8 bvk[2][4];
#pragma unroll
    for (int kk = 0; kk < 2; ++kk)
#pragma unroll
      for (int n = 0; n < 4; ++n) {
        int r = n * 16 + ln15, kc = kk * 4 + lq;
        bvk[kk][n] = *(const bf16x8*)(ktS + r * 128 + ((kc ^ (r & 7)) << 4));
      }
#pragma unroll
    for (int m = 0; m < 4; ++m) {
      f32x4 a1[4] = {};
#pragma unroll
      for (int kk = 0; kk < 2; ++kk)
#pragma unroll
        for (int n = 0; n < 4; ++n)
          a1[n] = __builtin_amdgcn_mfma_f32_16x16x32_bf16(pf[m][kk], bvk[kk][n], a1[n], 0, 0, 0);
#pragma unroll
      for (int n = 0; n < 4; ++n) {
        int nloc = n * 16 + ln15;
        int c = nloc >> 3, wb = (nloc & 7) * 2;
#pragma unroll
        for (int j = 0; j < 4; ++j) {
          int f = wid * 64 + m * 16 + lq * 4 + j;
          float v = a1[n][j];
          float o = v > 0.f ? v + 1.f : __expf(v);
          *(u16*)(kfS + f * 128 + ((c ^ (f & 7)) << 4) + wb) = f2bf(o);
        }
      }
    }
    __syncthreads();

    // ksum: thread tid owns f = tid
    {
      int f = tid;
      float s = 0.f;
#pragma unroll
      for (int c = 0; c < 8; ++c) {
        u16x8 v = *(const u16x8*)(kfS + f * 128 + ((c ^ (f & 7)) << 4));
#pragma unroll
        for (int j = 0; j < 8; ++j) s += bf2f(v[j]);
      }
      ksum_r += s;
    }
    // MFMA2: kv[f][d] += kfT @ vT^T (K = 64 n)
#pragma unroll
    for (int kk = 0; kk < 2; ++kk) {
      int kc = kk * 4 + lq;
      bf16x8 af[4], bv[4];
#pragma unroll
      for (int m = 0; m < 4; ++m) { int r = wid * 64 + m * 16 + ln15; af[m] = *(const bf16x8*)(kfS + r * 128 + ((kc ^ (r & 7)) << 4)); }
#pragma unroll
      for (int n = 0; n < 4; ++n) { int r = n * 16 + ln15; bv[n] = *(const bf16x8*)(vtS + r * 128 + ((kc ^ (r & 7)) << 4)); }
#pragma unroll
      for (int m = 0; m < 4; ++m)
#pragma unroll
        for (int n = 0; n < 4; ++n)
          acc2[m][n] = __builtin_amdgcn_mfma_f32_16x16x32_bf16(af[m], bv[n], acc2[m][n], 0, 0, 0);
    }
    __syncthreads();
  }

  const size_t pbase = ((size_t)bh * 16 + chunk) * 16384;
#pragma unroll
  for (int m = 0; m < 4; ++m)
#pragma unroll
    for (int n = 0; n < 4; ++n)
#pragma unroll
      for (int j = 0; j < 4; ++j) {
        int f = wid * 64 + m * 16 + lq * 4 + j;
        int d = n * 16 + ln15;
        kvpart[pbase + (size_t)f * 64 + d] = acc2[m][n][j];
      }
  ksumpart[((size_t)bh * 16 + chunk) * 256 + tid] = ksum_r;
}

// sum 16 chunk-partials; emit kvT bf16 [d][f] and ksum f32. grid 512 (bh*8+seg).
__global__ __launch_bounds__(256) void kv_finalize(const float* __restrict__ kvpart,
    const float* __restrict__ ksumpart, u16* __restrict__ kvT, float* __restrict__ ksum)
{
  int bx = blockIdx.x, bh = bx >> 3, seg = bx & 7, tid = threadIdx.x;
  const float* base = kvpart + (size_t)bh * 262144;
  u16* out = kvT + (size_t)bh * 16384;
  for (int i = seg * 2048 + tid; i < seg * 2048 + 2048; i += 256) {
    int d = i >> 8, f = i & 255;
    size_t o = (size_t)f * 64 + d;
    float s = 0.f;
#pragma unroll
    for (int c = 0; c < 16; ++c) s += base[(size_t)c * 16384 + o];
    out[i] = f2bf(s);
  }
  if (seg == 0) {
    float s = 0.f;
#pragma unroll
    for (int c = 0; c < 16; ++c) s += ksumpart[((size_t)bh * 16 + c) * 256 + tid];
    ksum[(size_t)bh * 256 + tid] = s;
  }
}

// ---------------------------------------------------------------------------
// fused_attn v2: proj B-frags in registers; per (bh, 64-n tile):
// qf=elu(q@projT^T)+1 (LDS), z=1/(qf.ksum+eps), attn=(qf@kvT^T)*z.
// ---------------------------------------------------------------------------
__global__ __launch_bounds__(256, 3)
void fused_attn(const u16* __restrict__ qkv, const u16* __restrict__ projT,
                const u16* __restrict__ kvT, const float* __restrict__ ksum,
                u16* __restrict__ attnb)
{
  __shared__ __align__(16) unsigned char qtS[8192];
  __shared__ __align__(16) unsigned char qfS[32768];
  __shared__ float zpart[64][4];
  __shared__ float zS[64];
  const int tid = threadIdx.x;
  const int bh = blockIdx.y, nt = blockIdx.x;
  const int b = bh >> 4, h = bh & 15;
  const int wid = tid >> 6, lane = tid & 63;
  const int ln15 = lane & 15, lq = lane >> 4;
  const int n0 = nt * 64;

  // proj B-frags: wave owns f in [wid*64,+64): pf[n][kk]
  bf16x8 pf[4][2];
#pragma unroll
  for (int n = 0; n < 4; ++n)
#pragma unroll
    for (int kk = 0; kk < 2; ++kk) {
      int f = wid * 64 + n * 16 + ln15;
      pf[n][kk] = *(const bf16x8*)(projT + (size_t)h * 16384 + (size_t)f * 64 + (kk * 4 + lq) * 8);
    }

  const u16* qg = qkv + ((size_t)b * 4096 + n0) * 3072 + h * 64;
#pragma unroll
  for (int i = 0; i < 2; ++i) {
    int c = i * 256 + tid; int r = c >> 3, ch = c & 7;
    load_lds16((const unsigned char*)(qg + (size_t)r * 3072) + ((ch ^ (r & 7)) << 4),
               qtS + r * 128 + ch * 16);
  }
  __syncthreads();

  // MFMA1 (m-outer): qf[n,f] for wave's f-range
#pragma unroll
  for (int m = 0; m < 4; ++m) {
    bf16x8 af[2];
#pragma unroll
    for (int kk = 0; kk < 2; ++kk) {
      int r = m * 16 + ln15, kc = kk * 4 + lq;
      af[kk] = *(const bf16x8*)(qtS + r * 128 + ((kc ^ (r & 7)) << 4));
    }
    f32x4 a1[4] = {};
#pragma unroll
    for (int kk = 0; kk < 2; ++kk)
#pragma unroll
      for (int n = 0; n < 4; ++n)
        a1[n] = __builtin_amdgcn_mfma_f32_16x16x32_bf16(af[kk], pf[n][kk], a1[n], 0, 0, 0);
#pragma unroll
    for (int n = 0; n < 4; ++n) {
      int f = wid * 64 + n * 16 + ln15;
      int c = f >> 3, wb = (f & 7) * 2;
#pragma unroll
      for (int j = 0; j < 4; ++j) {
        int row = m * 16 + lq * 4 + j;
        float v = a1[n][j];
        float o = v > 0.f ? v + 1.f : __expf(v);
        *(u16*)(qfS + row * 512 + ((c ^ (row & 7)) << 4) + wb) = f2bf(o);
      }
    }
  }
  __syncthreads();

  {
    int n = tid & 63, q = tid >> 6;
    const float* kp = ksum + (size_t)bh * 256;
    float s = 0.f;
#pragma unroll
    for (int c = q * 8; c < q * 8 + 8; ++c) {
      u16x8 v = *(const u16x8*)(qfS + n * 512 + ((c ^ (n & 7)) << 4));
#pragma unroll
      for (int j = 0; j < 8; ++j) s += bf2f(v[j]) * kp[c * 8 + j];
    }
    zpart[n][q] = s;
  }
  __syncthreads();
  if (tid < 64) zS[tid] = 1.f / (zpart[tid][0] + zpart[tid][1] + zpart[tid][2] + zpart[tid][3] + 1e-8f);
  __syncthreads();

  // MFMA2: wave owns n-rows [wid*16,+16); K=256 over f; kvT direct from L2
  f32x4 a2[4] = {};
  const u16* kvg = kvT + (size_t)bh * 16384;
#pragma unroll
  for (int kk = 0; kk < 8; ++kk) {
    int kc = kk * 4 + lq;
    int r = wid * 16 + ln15;
    bf16x8 af = *(const bf16x8*)(qfS + r * 512 + ((kc ^ (r & 7)) << 4));
#pragma unroll
    for (int nf = 0; nf < 4; ++nf) {
      int d = nf * 16 + ln15;
      bf16x8 bv = *(const bf16x8*)(kvg + (size_t)d * 256 + kc * 8);
      a2[nf] = __builtin_amdgcn_mfma_f32_16x16x32_bf16(af, bv, a2[nf], 0, 0, 0);
    }
  }
#pragma unroll
  for (int nf = 0; nf < 4; ++nf)
#pragma unroll
    for (int j = 0; j < 4; ++j) {
      int d = nf * 16 + ln15;
      int n = wid * 16 + lq * 4 + j;
      float v = a2[nf][j] * zS[n];
      attnb[((size_t)b * 4096 + n0 + n) * 1024 + h * 64 + d] = f2bf(v);
    }
}

__global__ __launch_bounds__(256) void cast_kernel(const float* __restrict__ in, u16* __restrict__ out, int n4)
{
  int i = blockIdx.x * 256 + threadIdx.x;
  if (i >= n4) return;
  float4 v = ((const float4*)in)[i];
  u16x4 o = { f2bf(v.x), f2bf(v.y), f2bf(v.z), f2bf(v.w) };
  ((u16x4*)out)[i] = o;
}

__global__ __launch_bounds__(256) void projt_kernel(const float* __restrict__ proj, u16* __restrict__ out)
{
  int i = blockIdx.x * 256 + threadIdx.x;
  int d = i & 63, f = (i >> 6) & 255, h = i >> 14;
  out[i] = f2bf(proj[((size_t)h * 64 + d) * 256 + f]);
}

__global__ __launch_bounds__(256) void ln_kernel(const float* __restrict__ in, const float* __restrict__ gamma,
                                                 const float* __restrict__ beta, float* __restrict__ outF,
                                                 u16* __restrict__ outB)
{
  int row = blockIdx.x, tid = threadIdx.x;
  float4 v = ((const float4*)(in + (size_t)row * 1024))[tid];
  float s = v.x + v.y + v.z + v.w;
  float q = v.x * v.x + v.y * v.y + v.z * v.z + v.w * v.w;
  for (int off = 32; off; off >>= 1) { s += __shfl_down(s, off); q += __shfl_down(q, off); }
  __shared__ float rs[4], rq[4];
  int wid = tid >> 6, lane = tid & 63;
  if (!lane) { rs[wid] = s; rq[wid] = q; }
  __syncthreads();
  s = rs[0] + rs[1] + rs[2] + rs[3];
  q = rq[0] + rq[1] + rq[2] + rq[3];
  float mu = s * (1.f / 1024.f);
  float rstd = rsqrtf(q * (1.f / 1024.f) - mu * mu + 1e-5f);
  float4 g = ((const float4*)gamma)[tid];
  float4 bb = ((const float4*)beta)[tid];
  float4 o;
  o.x = (v.x - mu) * rstd * g.x + bb.x;
  o.y = (v.y - mu) * rstd * g.y + bb.y;
  o.z = (v.z - mu) * rstd * g.z + bb.z;
  o.w = (v.w - mu) * rstd * g.w + bb.w;
  ((float4*)(outF + (size_t)row * 1024))[tid] = o;
  if (outB) {
    u16x4 ob = { f2bf(o.x), f2bf(o.y), f2bf(o.z), f2bf(o.w) };
    ((u16x4*)(outB + (size_t)row * 1024))[tid] = ob;
  }
}

// ---------------------------------------------------------------------------
// Workspace. d_out doubles as scratch:
//   phase A: xb (bf16 x) in d_out[0..33.5MB)
//   phase B: kvpart f32 = entire d_out (67.1MB, exactly 16M floats)
//   phase C: outproj result f32 (full overwrite) -> LN -> final
// ---------------------------------------------------------------------------
#define O_WQKVB   0L
#define O_WOUTB   6291456L
#define O_W1B     8388608L
#define O_W2B     16777216L
#define O_PROJT   25165824L
#define O_KSUM    25690112L
#define O_KSP     26804224L
#define O_KVB     27852800L
#define O_QFG     37289984L
#define O_QKVB    70844416L
#define O_ATTNB   171507712L
#define WS_NEED   205062144L

extern "C" void kernel_launch(void* const* d_in, const int* in_sizes, int n_in,
                              void* d_out, int out_size, void* d_ws, size_t ws_size,
                              hipStream_t stream)
{
  if (ws_size < (size_t)WS_NEED) return;

  const float* x     = (const float*)d_in[0];
  const float* proj  = (const float*)d_in[1];
  const float* wqkv  = (const float*)d_in[2];
  const float* wout  = (const float*)d_in[3];
  const float* bout  = (const float*)d_in[4];
  const float* gamma = (const float*)d_in[5];
  const float* beta  = (const float*)d_in[6];
  const float* w1    = (const float*)d_in[7];
  const float* b1    = (const float*)d_in[8];
  const float* w2    = (const float*)d_in[9];
  const float* b2    = (const float*)d_in[10];
  float* outp = (float*)d_out;
  char* ws = (char*)d_ws;

  u16* wqkvb  = (u16*)(ws + O_WQKVB);
  u16* woutb  = (u16*)(ws + O_WOUTB);
  u16* w1b    = (u16*)(ws + O_W1B);
  u16* w2b    = (u16*)(ws + O_W2B);
  u16* projTb = (u16*)(ws + O_PROJT);
  float* ksumf= (float*)(ws + O_KSUM);
  float* ksp  = (float*)(ws + O_KSP);
  u16* kvTb   = (u16*)(ws + O_KVB);
  u16* qkvb   = (u16*)(ws + O_QKVB);
  u16* attnb  = (u16*)(ws + O_ATTNB);
  u16* x1b    = (u16*)(ws + O_QFG);
  u16* hbu    = (u16*)(ws + O_QKVB);

  u16* xbD   = (u16*)d_out;
  float* kvp = (float*)d_out;

  cast_kernel<<<16384, 256, 0, stream>>>(x, xbD, 4194304);
  cast_kernel<<<3072, 256, 0, stream>>>(wqkv, wqkvb, 786432);
  cast_kernel<<<1024, 256, 0, stream>>>(wout, woutb, 262144);
  cast_kernel<<<4096, 256, 0, stream>>>(w1, w1b, 1048576);
  cast_kernel<<<4096, 256, 0, stream>>>(w2, w2b, 1048576);
  projt_kernel<<<1024, 256, 0, stream>>>(proj, projTb);

  gemm_nt<0><<<dim3(24, 128, 1), 256, 0, stream>>>(xbD, wqkvb, qkvb, nullptr, nullptr,
      16384, 3072, 1024, 1024, 1024, 3072, 0L, 0L, 0L, 0L, 0L, 0L, 1, 0L);

  fused_kv<<<dim3(16, 64), 256, 0, stream>>>(qkvb, projTb, kvp, ksp);
  kv_finalize<<<512, 256, 0, stream>>>(kvp, ksp, kvTb, ksumf);
  fused_attn<<<dim3(64, 64), 256, 0, stream>>>(qkvb, projTb, kvTb, ksumf, attnb);

  gemm_nt<3><<<dim3(8, 128, 1), 256, 0, stream>>>(attnb, woutb, outp, bout, x,
      16384, 1024, 1024, 1024, 1024, 1024, 0L, 0L, 0L, 0L, 0L, 0L, 1, 0L);

  ln_kernel<<<16384, 256, 0, stream>>>(outp, gamma, beta, outp, x1b);

  for (int half = 0; half < 2; ++half) {
    gemm_nt<4><<<dim3(16, 128, 1), 256, 0, stream>>>(x1b, w1b + (long)half * 2097152L, hbu,
        b1 + half * 2048, nullptr, 16384, 2048, 1024, 1024, 1024, 2048,
        0L, 0L, 0L, 0L, 0L, 0L, 1, 0L);
    if (half == 0) {
      gemm_nt<3><<<dim3(8, 128, 1), 256, 0, stream>>>(hbu, w2b + 0L, outp, b2, outp,
          16384, 1024, 2048, 2048, 4096, 1024, 0L, 0L, 0L, 0L, 0L, 0L, 1, 0L);
    } else {
      gemm_nt<5><<<dim3(8, 128, 1), 256, 0, stream>>>(hbu, w2b + 2048L, outp, nullptr, nullptr,
          16384, 1024, 2048, 2048, 4096, 1024, 0L, 0L, 0L, 0L, 0L, 0L, 1, 0L);
    }
  }

  ln_kernel<<<16384, 256, 0, stream>>>(outp, gamma, beta, outp, nullptr);
}

// Round 5
// 960.480 us; speedup vs baseline: 1.1714x; 1.1714x over previous
//
#include <hip/hip_runtime.h>
#include <math.h>

typedef unsigned short u16;
typedef __bf16 bf16x8 __attribute__((ext_vector_type(8)));
typedef float f32x4 __attribute__((ext_vector_type(4)));
typedef unsigned short u16x4 __attribute__((ext_vector_type(4)));
typedef unsigned short u16x8 __attribute__((ext_vector_type(8)));

#define DEV static __device__ __forceinline__

DEV float bf2f(u16 u) { union { unsigned int i; float f; } x; x.i = ((unsigned int)u) << 16; return x.f; }
DEV u16 f2bf(float f) { union { float f; unsigned int i; } x; x.f = f; unsigned int r = x.i + 0x7fffu + ((x.i >> 16) & 1u); return (u16)(r >> 16); }

DEV void load_lds16(const void* g, void* l) {
  __builtin_amdgcn_global_load_lds((__attribute__((address_space(1))) void*)g,
                                   (__attribute__((address_space(3))) void*)l, 16, 0, 0);
}

// ---------------------------------------------------------------------------
// Generic NT GEMM (proven, unchanged): C[m,n]=sum_k A[m,k]*B[n,k], 128x128,
// BK=64, 4 waves, MFMA 16x16x32, XOR swizzle both-sides, T1 XCD swizzle.
// EPI: 0 bf16 | 3 f32 v+aux0[col]+aux1 | 4 bias+gelu bf16 | 5 f32 += | 6 f32
// ---------------------------------------------------------------------------
template<int EPI>
__global__ __launch_bounds__(256, 2)
void gemm_nt(const u16* __restrict__ A, const u16* __restrict__ B, void* __restrict__ Cv,
             const float* __restrict__ aux0, const float* __restrict__ aux1,
             int M, int N, int K, int lda, int ldb, int ldc,
             long sAb, long sAh, long sBb, long sBh, long sCb, long sCh,
             int ksplit, long sKs)
{
  __shared__ __align__(16) unsigned char smem[32768];
  const int tid = threadIdx.x;
  const int bz = blockIdx.z;
  const long ob = bz >> 4, oh = bz & 15;
  const u16* Ab = A + ob * sAb + oh * sAh;
  const u16* Bb = B + ob * sBb + oh * sBh;
  int bx = blockIdx.x, by = blockIdx.y;
  if (ksplit == 1 && gridDim.z == 1) {
    int nwg = gridDim.x * gridDim.y;
    if ((nwg & 7) == 0) {
      int wg = by * gridDim.x + bx;
      int swz = (wg & 7) * (nwg >> 3) + (wg >> 3);
      bx = swz % gridDim.x; by = swz / gridDim.x;
    }
  }
  int mt = by, ks = 0;
  if (ksplit > 1) { ks = blockIdx.y; mt = 0; }
  const long cOff = ob * sCb + oh * sCh + (long)ks * sKs;
  const int m0 = mt * 128, n0 = bx * 128;
  const int kchunk = K / ksplit;
  const int klo = ks * kchunk, khi = klo + kchunk;
  const int wid = tid >> 6, lane = tid & 63;
  const int wr = wid >> 1, wc = wid & 1;
  const int ln15 = lane & 15, lq = lane >> 4;
  const int srow = tid >> 3, sch = tid & 7;

  f32x4 acc[4][4] = {};

  for (int k0 = klo; k0 < khi; k0 += 64) {
#pragma unroll
    for (int i = 0; i < 4; ++i) {
      int r = i * 32 + srow;
      int gr = m0 + r; gr = gr < M ? gr : M - 1;
      const unsigned char* src = (const unsigned char*)(Ab + (size_t)gr * lda + k0) + ((sch ^ (r & 7)) << 4);
      load_lds16(src, smem + r * 128 + (sch << 4));
    }
#pragma unroll
    for (int i = 0; i < 4; ++i) {
      int r = i * 32 + srow;
      int gc = n0 + r; gc = gc < N ? gc : N - 1;
      const unsigned char* src = (const unsigned char*)(Bb + (size_t)gc * ldb + k0) + ((sch ^ (r & 7)) << 4);
      load_lds16(src, smem + 16384 + r * 128 + (sch << 4));
    }
    __syncthreads();
#pragma unroll
    for (int kk = 0; kk < 2; ++kk) {
      bf16x8 af[4], bfv[4];
#pragma unroll
      for (int m = 0; m < 4; ++m) {
        int r = wr * 64 + m * 16 + ln15;
        int kc = kk * 4 + lq;
        af[m] = *(const bf16x8*)(smem + r * 128 + ((kc ^ (r & 7)) << 4));
      }
#pragma unroll
      for (int n = 0; n < 4; ++n) {
        int r = wc * 64 + n * 16 + ln15;
        int kc = kk * 4 + lq;
        bfv[n] = *(const bf16x8*)(smem + 16384 + r * 128 + ((kc ^ (r & 7)) << 4));
      }
#pragma unroll
      for (int m = 0; m < 4; ++m)
#pragma unroll
        for (int n = 0; n < 4; ++n)
          acc[m][n] = __builtin_amdgcn_mfma_f32_16x16x32_bf16(af[m], bfv[n], acc[m][n], 0, 0, 0);
    }
    __syncthreads();
  }

#pragma unroll
  for (int m = 0; m < 4; ++m) {
#pragma unroll
    for (int n = 0; n < 4; ++n) {
      int col = n0 + wc * 64 + n * 16 + ln15;
      if (col >= N) continue;
#pragma unroll
      for (int j = 0; j < 4; ++j) {
        int row = m0 + wr * 64 + m * 16 + lq * 4 + j;
        if (row >= M) continue;
        float v = acc[m][n][j];
        size_t idx = cOff + (size_t)row * ldc + col;
        if (EPI == 0) {
          ((u16*)Cv)[idx] = f2bf(v);
        } else if (EPI == 3) {
          ((float*)Cv)[idx] = v + aux0[col] + aux1[(size_t)row * ldc + col];
        } else if (EPI == 4) {
          float g = v + aux0[col];
          float o = 0.5f * g * (1.f + erff(g * 0.70710678118f));
          ((u16*)Cv)[idx] = f2bf(o);
        } else if (EPI == 5) {
          ((float*)Cv)[idx] += v;
        } else if (EPI == 6) {
          ((float*)Cv)[idx] = v;
        }
      }
    }
  }
}

// ---------------------------------------------------------------------------
// fused_kv v3: grid (16 chunks, 64 bh). proj A-frags in registers.
// Per 64-n tile: stage k (global_load_lds) + v reg-transposed into LDS;
// kfT=elu(projT@k^T)+1 -> kfS; ksum += rowsums; kv[f,d] += kfT@vT^T.
// Partials stored [d][f] via float4 (lane's acc f32x4 is f-contiguous) ->
// full-sector dense writes, no write-allocate RMW.
// ---------------------------------------------------------------------------
__global__ __launch_bounds__(256, 3)
void fused_kv(const u16* __restrict__ qkv, const u16* __restrict__ projT,
              float* __restrict__ kvpart, float* __restrict__ ksumpart)
{
  __shared__ __align__(16) unsigned char ktS[8192];
  __shared__ __align__(16) unsigned char vtS[8192];
  __shared__ __align__(16) unsigned char kfS[32768];
  const int tid = threadIdx.x;
  const int bh = blockIdx.y, chunk = blockIdx.x;
  const int b = bh >> 4, h = bh & 15;
  const int wid = tid >> 6, lane = tid & 63;
  const int ln15 = lane & 15, lq = lane >> 4;

  // proj fragments: wave owns f in [wid*64, +64): pf[m][kk]
  bf16x8 pf[4][2];
#pragma unroll
  for (int m = 0; m < 4; ++m)
#pragma unroll
    for (int kk = 0; kk < 2; ++kk) {
      int f = wid * 64 + m * 16 + ln15;
      pf[m][kk] = *(const bf16x8*)(projT + (size_t)h * 16384 + (size_t)f * 64 + (kk * 4 + lq) * 8);
    }

  float ksum_r = 0.f;
  f32x4 acc2[4][4] = {};

  for (int t = 0; t < 4; ++t) {
    int n0 = chunk * 256 + t * 64;
    const u16* kg = qkv + ((size_t)b * 4096 + n0) * 3072 + 1024 + h * 64;
#pragma unroll
    for (int i = 0; i < 2; ++i) {
      int c = i * 256 + tid; int r = c >> 3, ch = c & 7;
      load_lds16((const unsigned char*)(kg + (size_t)r * 3072) + ((ch ^ (r & 7)) << 4),
                 ktS + r * 128 + ch * 16);
    }
    {
      int nloc = tid >> 2, dblk = (tid & 3) * 16;
      const u16* vg = qkv + ((size_t)b * 4096 + n0 + nloc) * 3072 + 2048 + h * 64 + dblk;
      u16x8 v0 = *(const u16x8*)vg;
      u16x8 v1 = *(const u16x8*)(vg + 8);
      int cn = nloc >> 3, wb = (nloc & 7) * 2;
#pragma unroll
      for (int j = 0; j < 8; ++j) {
        int d = dblk + j;
        *(u16*)(vtS + d * 128 + ((cn ^ (d & 7)) << 4) + wb) = v0[j];
      }
#pragma unroll
      for (int j = 0; j < 8; ++j) {
        int d = dblk + 8 + j;
        *(u16*)(vtS + d * 128 + ((cn ^ (d & 7)) << 4) + wb) = v1[j];
      }
    }
    __syncthreads();

    // MFMA1 (m-outer): kf[f, nloc] then elu+1 -> kfS
    bf16x8 bvk[2][4];
#pragma unroll
    for (int kk = 0; kk < 2; ++kk)
#pragma unroll
      for (int n = 0; n < 4; ++n) {
        int r = n * 16 + ln15, kc = kk * 4 + lq;
        bvk[kk][n] = *(const bf16x8*)(ktS + r * 128 + ((kc ^ (r & 7)) << 4));
      }
#pragma unroll
    for (int m = 0; m < 4; ++m) {
      f32x4 a1[4] = {};
#pragma unroll
      for (int kk = 0; kk < 2; ++kk)
#pragma unroll
        for (int n = 0; n < 4; ++n)
          a1[n] = __builtin_amdgcn_mfma_f32_16x16x32_bf16(pf[m][kk], bvk[kk][n], a1[n], 0, 0, 0);
#pragma unroll
      for (int n = 0; n < 4; ++n) {
        int nloc = n * 16 + ln15;
        int c = nloc >> 3, wb = (nloc & 7) * 2;
#pragma unroll
        for (int j = 0; j < 4; ++j) {
          int f = wid * 64 + m * 16 + lq * 4 + j;
          float v = a1[n][j];
          float o = v > 0.f ? v + 1.f : __expf(v);
          *(u16*)(kfS + f * 128 + ((c ^ (f & 7)) << 4) + wb) = f2bf(o);
        }
      }
    }
    __syncthreads();

    // ksum: thread tid owns f = tid
    {
      int f = tid;
      float s = 0.f;
#pragma unroll
      for (int c = 0; c < 8; ++c) {
        u16x8 v = *(const u16x8*)(kfS + f * 128 + ((c ^ (f & 7)) << 4));
#pragma unroll
        for (int j = 0; j < 8; ++j) s += bf2f(v[j]);
      }
      ksum_r += s;
    }
    // MFMA2: kv[f][d] += kfT @ vT^T (K = 64 n)
#pragma unroll
    for (int kk = 0; kk < 2; ++kk) {
      int kc = kk * 4 + lq;
      bf16x8 af[4], bv[4];
#pragma unroll
      for (int m = 0; m < 4; ++m) { int r = wid * 64 + m * 16 + ln15; af[m] = *(const bf16x8*)(kfS + r * 128 + ((kc ^ (r & 7)) << 4)); }
#pragma unroll
      for (int n = 0; n < 4; ++n) { int r = n * 16 + ln15; bv[n] = *(const bf16x8*)(vtS + r * 128 + ((kc ^ (r & 7)) << 4)); }
#pragma unroll
      for (int m = 0; m < 4; ++m)
#pragma unroll
        for (int n = 0; n < 4; ++n)
          acc2[m][n] = __builtin_amdgcn_mfma_f32_16x16x32_bf16(af[m], bv[n], acc2[m][n], 0, 0, 0);
    }
    __syncthreads();
  }

  // dense [d][f] float4 partial store: lane's acc2[m][n] is f-contiguous
  const size_t pbase = ((size_t)bh * 16 + chunk) * 16384;
#pragma unroll
  for (int m = 0; m < 4; ++m)
#pragma unroll
    for (int n = 0; n < 4; ++n) {
      int d = n * 16 + ln15;
      int f = wid * 64 + m * 16 + lq * 4;
      *(f32x4*)(kvpart + pbase + (size_t)d * 256 + f) = acc2[m][n];
    }
  ksumpart[((size_t)bh * 16 + chunk) * 256 + tid] = ksum_r;
}

// sum 16 chunk-partials in [d][f] layout; fully coalesced both sides.
// grid 256 = bh*4 + dq (dq = 16-d slab).
__global__ __launch_bounds__(256) void kv_finalize(const float* __restrict__ kvpart,
    const float* __restrict__ ksumpart, u16* __restrict__ kvT, float* __restrict__ ksum)
{
  int bx = blockIdx.x, bh = bx >> 2, dq = bx & 3, tid = threadIdx.x;
  const float* base = kvpart + (size_t)bh * 262144;
  u16* out = kvT + (size_t)bh * 16384;
#pragma unroll
  for (int k = 0; k < 16; ++k) {
    int idx = dq * 4096 + k * 256 + tid;
    float s = 0.f;
#pragma unroll
    for (int c = 0; c < 16; ++c) s += base[(size_t)c * 16384 + idx];
    out[idx] = f2bf(s);
  }
  if (dq == 0) {
    float s = 0.f;
#pragma unroll
    for (int c = 0; c < 16; ++c) s += ksumpart[((size_t)bh * 16 + c) * 256 + tid];
    ksum[(size_t)bh * 256 + tid] = s;
  }
}

// ---------------------------------------------------------------------------
// fused_attn (unchanged): proj B-frags in registers; per (bh, 64-n tile):
// qf=elu(q@projT^T)+1 (LDS), z=1/(qf.ksum+eps), attn=(qf@kvT^T)*z.
// ---------------------------------------------------------------------------
__global__ __launch_bounds__(256, 3)
void fused_attn(const u16* __restrict__ qkv, const u16* __restrict__ projT,
                const u16* __restrict__ kvT, const float* __restrict__ ksum,
                u16* __restrict__ attnb)
{
  __shared__ __align__(16) unsigned char qtS[8192];
  __shared__ __align__(16) unsigned char qfS[32768];
  __shared__ float zpart[64][4];
  __shared__ float zS[64];
  const int tid = threadIdx.x;
  const int bh = blockIdx.y, nt = blockIdx.x;
  const int b = bh >> 4, h = bh & 15;
  const int wid = tid >> 6, lane = tid & 63;
  const int ln15 = lane & 15, lq = lane >> 4;
  const int n0 = nt * 64;

  bf16x8 pf[4][2];
#pragma unroll
  for (int n = 0; n < 4; ++n)
#pragma unroll
    for (int kk = 0; kk < 2; ++kk) {
      int f = wid * 64 + n * 16 + ln15;
      pf[n][kk] = *(const bf16x8*)(projT + (size_t)h * 16384 + (size_t)f * 64 + (kk * 4 + lq) * 8);
    }

  const u16* qg = qkv + ((size_t)b * 4096 + n0) * 3072 + h * 64;
#pragma unroll
  for (int i = 0; i < 2; ++i) {
    int c = i * 256 + tid; int r = c >> 3, ch = c & 7;
    load_lds16((const unsigned char*)(qg + (size_t)r * 3072) + ((ch ^ (r & 7)) << 4),
               qtS + r * 128 + ch * 16);
  }
  __syncthreads();

#pragma unroll
  for (int m = 0; m < 4; ++m) {
    bf16x8 af[2];
#pragma unroll
    for (int kk = 0; kk < 2; ++kk) {
      int r = m * 16 + ln15, kc = kk * 4 + lq;
      af[kk] = *(const bf16x8*)(qtS + r * 128 + ((kc ^ (r & 7)) << 4));
    }
    f32x4 a1[4] = {};
#pragma unroll
    for (int kk = 0; kk < 2; ++kk)
#pragma unroll
      for (int n = 0; n < 4; ++n)
        a1[n] = __builtin_amdgcn_mfma_f32_16x16x32_bf16(af[kk], pf[n][kk], a1[n], 0, 0, 0);
#pragma unroll
    for (int n = 0; n < 4; ++n) {
      int f = wid * 64 + n * 16 + ln15;
      int c = f >> 3, wb = (f & 7) * 2;
#pragma unroll
      for (int j = 0; j < 4; ++j) {
        int row = m * 16 + lq * 4 + j;
        float v = a1[n][j];
        float o = v > 0.f ? v + 1.f : __expf(v);
        *(u16*)(qfS + row * 512 + ((c ^ (row & 7)) << 4) + wb) = f2bf(o);
      }
    }
  }
  __syncthreads();

  {
    int n = tid & 63, q = tid >> 6;
    const float* kp = ksum + (size_t)bh * 256;
    float s = 0.f;
#pragma unroll
    for (int c = q * 8; c < q * 8 + 8; ++c) {
      u16x8 v = *(const u16x8*)(qfS + n * 512 + ((c ^ (n & 7)) << 4));
#pragma unroll
      for (int j = 0; j < 8; ++j) s += bf2f(v[j]) * kp[c * 8 + j];
    }
    zpart[n][q] = s;
  }
  __syncthreads();
  if (tid < 64) zS[tid] = 1.f / (zpart[tid][0] + zpart[tid][1] + zpart[tid][2] + zpart[tid][3] + 1e-8f);
  __syncthreads();

  f32x4 a2[4] = {};
  const u16* kvg = kvT + (size_t)bh * 16384;
#pragma unroll
  for (int kk = 0; kk < 8; ++kk) {
    int kc = kk * 4 + lq;
    int r = wid * 16 + ln15;
    bf16x8 af = *(const bf16x8*)(qfS + r * 512 + ((kc ^ (r & 7)) << 4));
#pragma unroll
    for (int nf = 0; nf < 4; ++nf) {
      int d = nf * 16 + ln15;
      bf16x8 bv = *(const bf16x8*)(kvg + (size_t)d * 256 + kc * 8);
      a2[nf] = __builtin_amdgcn_mfma_f32_16x16x32_bf16(af, bv, a2[nf], 0, 0, 0);
    }
  }
#pragma unroll
  for (int nf = 0; nf < 4; ++nf)
#pragma unroll
    for (int j = 0; j < 4; ++j) {
      int d = nf * 16 + ln15;
      int n = wid * 16 + lq * 4 + j;
      float v = a2[nf][j] * zS[n];
      attnb[((size_t)b * 4096 + n0 + n) * 1024 + h * 64 + d] = f2bf(v);
    }
}

__global__ __launch_bounds__(256) void cast_kernel(const float* __restrict__ in, u16* __restrict__ out, int n4)
{
  int i = blockIdx.x * 256 + threadIdx.x;
  if (i >= n4) return;
  float4 v = ((const float4*)in)[i];
  u16x4 o = { f2bf(v.x), f2bf(v.y), f2bf(v.z), f2bf(v.w) };
  ((u16x4*)out)[i] = o;
}

__global__ __launch_bounds__(256) void projt_kernel(const float* __restrict__ proj, u16* __restrict__ out)
{
  int i = blockIdx.x * 256 + threadIdx.x;
  int d = i & 63, f = (i >> 6) & 255, h = i >> 14;
  out[i] = f2bf(proj[((size_t)h * 64 + d) * 256 + f]);
}

__global__ __launch_bounds__(256) void ln_kernel(const float* __restrict__ in, const float* __restrict__ gamma,
                                                 const float* __restrict__ beta, float* __restrict__ outF,
                                                 u16* __restrict__ outB)
{
  int row = blockIdx.x, tid = threadIdx.x;
  float4 v = ((const float4*)(in + (size_t)row * 1024))[tid];
  float s = v.x + v.y + v.z + v.w;
  float q = v.x * v.x + v.y * v.y + v.z * v.z + v.w * v.w;
  for (int off = 32; off; off >>= 1) { s += __shfl_down(s, off); q += __shfl_down(q, off); }
  __shared__ float rs[4], rq[4];
  int wid = tid >> 6, lane = tid & 63;
  if (!lane) { rs[wid] = s; rq[wid] = q; }
  __syncthreads();
  s = rs[0] + rs[1] + rs[2] + rs[3];
  q = rq[0] + rq[1] + rq[2] + rq[3];
  float mu = s * (1.f / 1024.f);
  float rstd = rsqrtf(q * (1.f / 1024.f) - mu * mu + 1e-5f);
  float4 g = ((const float4*)gamma)[tid];
  float4 bb = ((const float4*)beta)[tid];
  float4 o;
  o.x = (v.x - mu) * rstd * g.x + bb.x;
  o.y = (v.y - mu) * rstd * g.y + bb.y;
  o.z = (v.z - mu) * rstd * g.z + bb.z;
  o.w = (v.w - mu) * rstd * g.w + bb.w;
  ((float4*)(outF + (size_t)row * 1024))[tid] = o;
  if (outB) {
    u16x4 ob = { f2bf(o.x), f2bf(o.y), f2bf(o.z), f2bf(o.w) };
    ((u16x4*)(outB + (size_t)row * 1024))[tid] = ob;
  }
}

// ---------------------------------------------------------------------------
// Workspace. d_out doubles as scratch:
//   phase A: xb (bf16 x) in d_out[0..33.5MB)
//   phase B: kvpart f32 [bh][chunk][d][f] = entire d_out (67.1MB)
//   phase C: outproj result f32 (full overwrite) -> LN -> final
// ---------------------------------------------------------------------------
#define O_WQKVB   0L
#define O_WOUTB   6291456L
#define O_W1B     8388608L
#define O_W2B     16777216L
#define O_PROJT   25165824L
#define O_KSUM    25690112L
#define O_KSP     26804224L
#define O_KVB     27852800L
#define O_QFG     37289984L
#define O_QKVB    70844416L
#define O_ATTNB   171507712L
#define WS_NEED   205062144L

extern "C" void kernel_launch(void* const* d_in, const int* in_sizes, int n_in,
                              void* d_out, int out_size, void* d_ws, size_t ws_size,
                              hipStream_t stream)
{
  if (ws_size < (size_t)WS_NEED) return;

  const float* x     = (const float*)d_in[0];
  const float* proj  = (const float*)d_in[1];
  const float* wqkv  = (const float*)d_in[2];
  const float* wout  = (const float*)d_in[3];
  const float* bout  = (const float*)d_in[4];
  const float* gamma = (const float*)d_in[5];
  const float* beta  = (const float*)d_in[6];
  const float* w1    = (const float*)d_in[7];
  const float* b1    = (const float*)d_in[8];
  const float* w2    = (const float*)d_in[9];
  const float* b2    = (const float*)d_in[10];
  float* outp = (float*)d_out;
  char* ws = (char*)d_ws;

  u16* wqkvb  = (u16*)(ws + O_WQKVB);
  u16* woutb  = (u16*)(ws + O_WOUTB);
  u16* w1b    = (u16*)(ws + O_W1B);
  u16* w2b    = (u16*)(ws + O_W2B);
  u16* projTb = (u16*)(ws + O_PROJT);
  float* ksumf= (float*)(ws + O_KSUM);
  float* ksp  = (float*)(ws + O_KSP);
  u16* kvTb   = (u16*)(ws + O_KVB);
  u16* qkvb   = (u16*)(ws + O_QKVB);
  u16* attnb  = (u16*)(ws + O_ATTNB);
  u16* x1b    = (u16*)(ws + O_QFG);
  u16* hbu    = (u16*)(ws + O_QKVB);

  u16* xbD   = (u16*)d_out;
  float* kvp = (float*)d_out;

  cast_kernel<<<16384, 256, 0, stream>>>(x, xbD, 4194304);
  cast_kernel<<<3072, 256, 0, stream>>>(wqkv, wqkvb, 786432);
  cast_kernel<<<1024, 256, 0, stream>>>(wout, woutb, 262144);
  cast_kernel<<<4096, 256, 0, stream>>>(w1, w1b, 1048576);
  cast_kernel<<<4096, 256, 0, stream>>>(w2, w2b, 1048576);
  projt_kernel<<<1024, 256, 0, stream>>>(proj, projTb);

  gemm_nt<0><<<dim3(24, 128, 1), 256, 0, stream>>>(xbD, wqkvb, qkvb, nullptr, nullptr,
      16384, 3072, 1024, 1024, 1024, 3072, 0L, 0L, 0L, 0L, 0L, 0L, 1, 0L);

  fused_kv<<<dim3(16, 64), 256, 0, stream>>>(qkvb, projTb, kvp, ksp);
  kv_finalize<<<256, 256, 0, stream>>>(kvp, ksp, kvTb, ksumf);
  fused_attn<<<dim3(64, 64), 256, 0, stream>>>(qkvb, projTb, kvTb, ksumf, attnb);

  gemm_nt<3><<<dim3(8, 128, 1), 256, 0, stream>>>(attnb, woutb, outp, bout, x,
      16384, 1024, 1024, 1024, 1024, 1024, 0L, 0L, 0L, 0L, 0L, 0L, 1, 0L);

  ln_kernel<<<16384, 256, 0, stream>>>(outp, gamma, beta, outp, x1b);

  for (int half = 0; half < 2; ++half) {
    gemm_nt<4><<<dim3(16, 128, 1), 256, 0, stream>>>(x1b, w1b + (long)half * 2097152L, hbu,
        b1 + half * 2048, nullptr, 16384, 2048, 1024, 1024, 1024, 2048,
        0L, 0L, 0L, 0L, 0L, 0L, 1, 0L);
    if (half == 0) {
      gemm_nt<3><<<dim3(8, 128, 1), 256, 0, stream>>>(hbu, w2b + 0L, outp, b2, outp,
          16384, 1024, 2048, 2048, 4096, 1024, 0L, 0L, 0L, 0L, 0L, 0L, 1, 0L);
    } else {
      gemm_nt<5><<<dim3(8, 128, 1), 256, 0, stream>>>(hbu, w2b + 2048L, outp, nullptr, nullptr,
          16384, 1024, 2048, 2048, 4096, 1024, 0L, 0L, 0L, 0L, 0L, 0L, 1, 0L);
    }
  }

  ln_kernel<<<16384, 256, 0, stream>>>(outp, gamma, beta, outp, nullptr);
}

// Round 6
// 820.430 us; speedup vs baseline: 1.3713x; 1.1707x over previous
//
#include <hip/hip_runtime.h>
#include <math.h>

typedef unsigned short u16;
typedef __bf16 bf16x8 __attribute__((ext_vector_type(8)));
typedef float f32x4 __attribute__((ext_vector_type(4)));
typedef unsigned short u16x4 __attribute__((ext_vector_type(4)));
typedef unsigned short u16x8 __attribute__((ext_vector_type(8)));

#define DEV static __device__ __forceinline__

DEV float bf2f(u16 u) { union { unsigned int i; float f; } x; x.i = ((unsigned int)u) << 16; return x.f; }
DEV u16 f2bf(float f) { union { float f; unsigned int i; } x; x.f = f; unsigned int r = x.i + 0x7fffu + ((x.i >> 16) & 1u); return (u16)(r >> 16); }

DEV void load_lds16(const void* g, void* l) {
  __builtin_amdgcn_global_load_lds((__attribute__((address_space(1))) void*)g,
                                   (__attribute__((address_space(3))) void*)l, 16, 0, 0);
}

// ---------------------------------------------------------------------------
// Generic NT GEMM (proven, unchanged): C[m,n]=sum_k A[m,k]*B[n,k], 128x128,
// BK=64, 4 waves, MFMA 16x16x32, XOR swizzle both-sides, T1 XCD swizzle.
// EPI: 0 bf16 | 3 f32 v+aux0[col]+aux1 | 4 bias+gelu bf16 | 5 f32 += | 6 f32
// ---------------------------------------------------------------------------
template<int EPI>
__global__ __launch_bounds__(256, 2)
void gemm_nt(const u16* __restrict__ A, const u16* __restrict__ B, void* __restrict__ Cv,
             const float* __restrict__ aux0, const float* __restrict__ aux1,
             int M, int N, int K, int lda, int ldb, int ldc,
             long sAb, long sAh, long sBb, long sBh, long sCb, long sCh,
             int ksplit, long sKs)
{
  __shared__ __align__(16) unsigned char smem[32768];
  const int tid = threadIdx.x;
  const int bz = blockIdx.z;
  const long ob = bz >> 4, oh = bz & 15;
  const u16* Ab = A + ob * sAb + oh * sAh;
  const u16* Bb = B + ob * sBb + oh * sBh;
  int bx = blockIdx.x, by = blockIdx.y;
  if (ksplit == 1 && gridDim.z == 1) {
    int nwg = gridDim.x * gridDim.y;
    if ((nwg & 7) == 0) {
      int wg = by * gridDim.x + bx;
      int swz = (wg & 7) * (nwg >> 3) + (wg >> 3);
      bx = swz % gridDim.x; by = swz / gridDim.x;
    }
  }
  int mt = by, ks = 0;
  if (ksplit > 1) { ks = blockIdx.y; mt = 0; }
  const long cOff = ob * sCb + oh * sCh + (long)ks * sKs;
  const int m0 = mt * 128, n0 = bx * 128;
  const int kchunk = K / ksplit;
  const int klo = ks * kchunk, khi = klo + kchunk;
  const int wid = tid >> 6, lane = tid & 63;
  const int wr = wid >> 1, wc = wid & 1;
  const int ln15 = lane & 15, lq = lane >> 4;
  const int srow = tid >> 3, sch = tid & 7;

  f32x4 acc[4][4] = {};

  for (int k0 = klo; k0 < khi; k0 += 64) {
#pragma unroll
    for (int i = 0; i < 4; ++i) {
      int r = i * 32 + srow;
      int gr = m0 + r; gr = gr < M ? gr : M - 1;
      const unsigned char* src = (const unsigned char*)(Ab + (size_t)gr * lda + k0) + ((sch ^ (r & 7)) << 4);
      load_lds16(src, smem + r * 128 + (sch << 4));
    }
#pragma unroll
    for (int i = 0; i < 4; ++i) {
      int r = i * 32 + srow;
      int gc = n0 + r; gc = gc < N ? gc : N - 1;
      const unsigned char* src = (const unsigned char*)(Bb + (size_t)gc * ldb + k0) + ((sch ^ (r & 7)) << 4);
      load_lds16(src, smem + 16384 + r * 128 + (sch << 4));
    }
    __syncthreads();
#pragma unroll
    for (int kk = 0; kk < 2; ++kk) {
      bf16x8 af[4], bfv[4];
#pragma unroll
      for (int m = 0; m < 4; ++m) {
        int r = wr * 64 + m * 16 + ln15;
        int kc = kk * 4 + lq;
        af[m] = *(const bf16x8*)(smem + r * 128 + ((kc ^ (r & 7)) << 4));
      }
#pragma unroll
      for (int n = 0; n < 4; ++n) {
        int r = wc * 64 + n * 16 + ln15;
        int kc = kk * 4 + lq;
        bfv[n] = *(const bf16x8*)(smem + 16384 + r * 128 + ((kc ^ (r & 7)) << 4));
      }
#pragma unroll
      for (int m = 0; m < 4; ++m)
#pragma unroll
        for (int n = 0; n < 4; ++n)
          acc[m][n] = __builtin_amdgcn_mfma_f32_16x16x32_bf16(af[m], bfv[n], acc[m][n], 0, 0, 0);
    }
    __syncthreads();
  }

#pragma unroll
  for (int m = 0; m < 4; ++m) {
#pragma unroll
    for (int n = 0; n < 4; ++n) {
      int col = n0 + wc * 64 + n * 16 + ln15;
      if (col >= N) continue;
#pragma unroll
      for (int j = 0; j < 4; ++j) {
        int row = m0 + wr * 64 + m * 16 + lq * 4 + j;
        if (row >= M) continue;
        float v = acc[m][n][j];
        size_t idx = cOff + (size_t)row * ldc + col;
        if (EPI == 0) {
          ((u16*)Cv)[idx] = f2bf(v);
        } else if (EPI == 3) {
          ((float*)Cv)[idx] = v + aux0[col] + aux1[(size_t)row * ldc + col];
        } else if (EPI == 4) {
          float g = v + aux0[col];
          float o = 0.5f * g * (1.f + erff(g * 0.70710678118f));
          ((u16*)Cv)[idx] = f2bf(o);
        } else if (EPI == 5) {
          ((float*)Cv)[idx] += v;
        } else if (EPI == 6) {
          ((float*)Cv)[idx] = v;
        }
      }
    }
  }
}

// ---------------------------------------------------------------------------
// fused_kv v4: grid (8 chunks x 64 bh), 512 n per block, software-pipelined.
// Double-buffered ktS/vtS; tile t+1's global loads issued before tile t's
// MFMAs (T14); 2 barriers/tile. proj A-frags in registers.
// Partials written [d][f] full-line coalesced via LDS slab staging.
// ---------------------------------------------------------------------------
__global__ __launch_bounds__(256, 2)
void fused_kv(const u16* __restrict__ qkv, const u16* __restrict__ projT,
              float* __restrict__ kvpart, float* __restrict__ ksumpart)
{
  __shared__ __align__(16) unsigned char ktS[2][8192];
  __shared__ __align__(16) unsigned char vtS[2][8192];
  __shared__ __align__(16) unsigned char kfS[32768];
  const int tid = threadIdx.x;
  const int bh = blockIdx.y, chunk = blockIdx.x;
  const int b = bh >> 4, h = bh & 15;
  const int wid = tid >> 6, lane = tid & 63;
  const int ln15 = lane & 15, lq = lane >> 4;
  const int vN = tid >> 2, vD = (tid & 3) * 16;   // v-load: row, d-block
  const int vCn = vN >> 3, vWb = (vN & 7) * 2;    // vtS swizzle components

  // proj fragments: wave owns f in [wid*64, +64): pf[m][kk]
  bf16x8 pf[4][2];
#pragma unroll
  for (int m = 0; m < 4; ++m)
#pragma unroll
    for (int kk = 0; kk < 2; ++kk) {
      int f = wid * 64 + m * 16 + ln15;
      pf[m][kk] = *(const bf16x8*)(projT + (size_t)h * 16384 + (size_t)f * 64 + (kk * 4 + lq) * 8);
    }

  float ksum_r = 0.f;
  f32x4 acc2[4][4] = {};
  const int nbase = chunk * 512;

  // ---- prologue: stage tile 0 into buffer 0 ----
  {
    const u16* kg = qkv + ((size_t)b * 4096 + nbase) * 3072 + 1024 + h * 64;
#pragma unroll
    for (int i = 0; i < 2; ++i) {
      int c = i * 256 + tid; int r = c >> 3, ch = c & 7;
      load_lds16((const unsigned char*)(kg + (size_t)r * 3072) + ((ch ^ (r & 7)) << 4),
                 ktS[0] + r * 128 + ch * 16);
    }
    const u16* vg = qkv + ((size_t)b * 4096 + nbase + vN) * 3072 + 2048 + h * 64 + vD;
    u16x8 va = *(const u16x8*)vg;
    u16x8 vb = *(const u16x8*)(vg + 8);
#pragma unroll
    for (int j = 0; j < 8; ++j) {
      int d = vD + j;
      *(u16*)(vtS[0] + d * 128 + ((vCn ^ (d & 7)) << 4) + vWb) = va[j];
    }
#pragma unroll
    for (int j = 0; j < 8; ++j) {
      int d = vD + 8 + j;
      *(u16*)(vtS[0] + d * 128 + ((vCn ^ (d & 7)) << 4) + vWb) = vb[j];
    }
  }
  __syncthreads();

  // ---- main loop: 8 tiles, double-buffered ----
  for (int t = 0; t < 8; ++t) {
    const int cur = t & 1, nxt = cur ^ 1;
    u16x8 va, vb;
    const bool havenext = (t + 1 < 8);
    if (havenext) {
      int n1 = nbase + (t + 1) * 64;
      const u16* kg = qkv + ((size_t)b * 4096 + n1) * 3072 + 1024 + h * 64;
#pragma unroll
      for (int i = 0; i < 2; ++i) {
        int c = i * 256 + tid; int r = c >> 3, ch = c & 7;
        load_lds16((const unsigned char*)(kg + (size_t)r * 3072) + ((ch ^ (r & 7)) << 4),
                   ktS[nxt] + r * 128 + ch * 16);
      }
      const u16* vg = qkv + ((size_t)b * 4096 + n1 + vN) * 3072 + 2048 + h * 64 + vD;
      va = *(const u16x8*)vg;
      vb = *(const u16x8*)(vg + 8);
    }

    // MFMA1 (m-outer): kf[f, nloc] from ktS[cur], elu+1 -> kfS
    bf16x8 bvk[2][4];
#pragma unroll
    for (int kk = 0; kk < 2; ++kk)
#pragma unroll
      for (int n = 0; n < 4; ++n) {
        int r = n * 16 + ln15, kc = kk * 4 + lq;
        bvk[kk][n] = *(const bf16x8*)(ktS[cur] + r * 128 + ((kc ^ (r & 7)) << 4));
      }
#pragma unroll
    for (int m = 0; m < 4; ++m) {
      f32x4 a1[4] = {};
#pragma unroll
      for (int kk = 0; kk < 2; ++kk)
#pragma unroll
        for (int n = 0; n < 4; ++n)
          a1[n] = __builtin_amdgcn_mfma_f32_16x16x32_bf16(pf[m][kk], bvk[kk][n], a1[n], 0, 0, 0);
#pragma unroll
      for (int n = 0; n < 4; ++n) {
        int nloc = n * 16 + ln15;
        int c = nloc >> 3, wb = (nloc & 7) * 2;
#pragma unroll
        for (int j = 0; j < 4; ++j) {
          int f = wid * 64 + m * 16 + lq * 4 + j;
          float v = a1[n][j];
          float o = v > 0.f ? v + 1.f : __expf(v);
          *(u16*)(kfS + f * 128 + ((c ^ (f & 7)) << 4) + wb) = f2bf(o);
        }
      }
    }
    __syncthreads();   // barrier A: kfS visible; ktS[cur] reads done

    // ksum: thread tid owns f = tid
    {
      int f = tid;
      float s = 0.f;
#pragma unroll
      for (int c = 0; c < 8; ++c) {
        u16x8 v = *(const u16x8*)(kfS + f * 128 + ((c ^ (f & 7)) << 4));
#pragma unroll
        for (int j = 0; j < 8; ++j) s += bf2f(v[j]);
      }
      ksum_r += s;
    }
    // MFMA2: kv[f][d] += kfT @ vT^T (K = 64 n) from kfS + vtS[cur]
#pragma unroll
    for (int kk = 0; kk < 2; ++kk) {
      int kc = kk * 4 + lq;
      bf16x8 af[4], bv[4];
#pragma unroll
      for (int m = 0; m < 4; ++m) { int r = wid * 64 + m * 16 + ln15; af[m] = *(const bf16x8*)(kfS + r * 128 + ((kc ^ (r & 7)) << 4)); }
#pragma unroll
      for (int n = 0; n < 4; ++n) { int r = n * 16 + ln15; bv[n] = *(const bf16x8*)(vtS[cur] + r * 128 + ((kc ^ (r & 7)) << 4)); }
#pragma unroll
      for (int m = 0; m < 4; ++m)
#pragma unroll
        for (int n = 0; n < 4; ++n)
          acc2[m][n] = __builtin_amdgcn_mfma_f32_16x16x32_bf16(af[m], bv[n], acc2[m][n], 0, 0, 0);
    }
    // write next tile's v (regs arrived under MFMA cover)
    if (havenext) {
#pragma unroll
      for (int j = 0; j < 8; ++j) {
        int d = vD + j;
        *(u16*)(vtS[nxt] + d * 128 + ((vCn ^ (d & 7)) << 4) + vWb) = va[j];
      }
#pragma unroll
      for (int j = 0; j < 8; ++j) {
        int d = vD + 8 + j;
        *(u16*)(vtS[nxt] + d * 128 + ((vCn ^ (d & 7)) << 4) + vWb) = vb[j];
      }
    }
    __syncthreads();   // barrier B: vtS[nxt]+ktS[nxt] ready; vtS[cur] reads done
  }

  // ---- partial store: [d][f] full-line coalesced via kfS slab staging ----
  const size_t pbase = ((size_t)bh * 8 + chunk) * 16384;
#pragma unroll
  for (int half = 0; half < 2; ++half) {
#pragma unroll
    for (int m = 0; m < 4; ++m)
#pragma unroll
      for (int n2 = 0; n2 < 2; ++n2) {
        int n = half * 2 + n2;
        int dloc = n2 * 16 + ln15;
        int f = wid * 64 + m * 16 + lq * 4;
        *(f32x4*)(kfS + dloc * 1024 + ((f * 4) ^ ((dloc & 7) << 4))) = acc2[m][n];
      }
    __syncthreads();
#pragma unroll
    for (int k = 0; k < 8; ++k) {
      int dloc = k * 4 + wid;
      f32x4 val = *(const f32x4*)(kfS + dloc * 1024 + ((lane * 16) ^ ((dloc & 7) << 4)));
      *(f32x4*)(kvpart + pbase + (size_t)(half * 32 + dloc) * 256 + lane * 4) = val;
    }
    __syncthreads();
  }
  ksumpart[((size_t)bh * 8 + chunk) * 256 + tid] = ksum_r;
}

// sum 8 chunk-partials in [d][f] layout; coalesced both sides. grid 256.
__global__ __launch_bounds__(256) void kv_finalize(const float* __restrict__ kvpart,
    const float* __restrict__ ksumpart, u16* __restrict__ kvT, float* __restrict__ ksum)
{
  int bx = blockIdx.x, bh = bx >> 2, dq = bx & 3, tid = threadIdx.x;
  const float* base = kvpart + (size_t)bh * 131072;
  u16* out = kvT + (size_t)bh * 16384;
#pragma unroll
  for (int k = 0; k < 16; ++k) {
    int idx = dq * 4096 + k * 256 + tid;
    float s = 0.f;
#pragma unroll
    for (int c = 0; c < 8; ++c) s += base[(size_t)c * 16384 + idx];
    out[idx] = f2bf(s);
  }
  if (dq == 0) {
    float s = 0.f;
#pragma unroll
    for (int c = 0; c < 8; ++c) s += ksumpart[((size_t)bh * 8 + c) * 256 + tid];
    ksum[(size_t)bh * 256 + tid] = s;
  }
}

// ---------------------------------------------------------------------------
// fused_attn (unchanged): proj B-frags in registers; per (bh, 64-n tile):
// qf=elu(q@projT^T)+1 (LDS), z=1/(qf.ksum+eps), attn=(qf@kvT^T)*z.
// ---------------------------------------------------------------------------
__global__ __launch_bounds__(256, 3)
void fused_attn(const u16* __restrict__ qkv, const u16* __restrict__ projT,
                const u16* __restrict__ kvT, const float* __restrict__ ksum,
                u16* __restrict__ attnb)
{
  __shared__ __align__(16) unsigned char qtS[8192];
  __shared__ __align__(16) unsigned char qfS[32768];
  __shared__ float zpart[64][4];
  __shared__ float zS[64];
  const int tid = threadIdx.x;
  const int bh = blockIdx.y, nt = blockIdx.x;
  const int b = bh >> 4, h = bh & 15;
  const int wid = tid >> 6, lane = tid & 63;
  const int ln15 = lane & 15, lq = lane >> 4;
  const int n0 = nt * 64;

  bf16x8 pf[4][2];
#pragma unroll
  for (int n = 0; n < 4; ++n)
#pragma unroll
    for (int kk = 0; kk < 2; ++kk) {
      int f = wid * 64 + n * 16 + ln15;
      pf[n][kk] = *(const bf16x8*)(projT + (size_t)h * 16384 + (size_t)f * 64 + (kk * 4 + lq) * 8);
    }

  const u16* qg = qkv + ((size_t)b * 4096 + n0) * 3072 + h * 64;
#pragma unroll
  for (int i = 0; i < 2; ++i) {
    int c = i * 256 + tid; int r = c >> 3, ch = c & 7;
    load_lds16((const unsigned char*)(qg + (size_t)r * 3072) + ((ch ^ (r & 7)) << 4),
               qtS + r * 128 + ch * 16);
  }
  __syncthreads();

#pragma unroll
  for (int m = 0; m < 4; ++m) {
    bf16x8 af[2];
#pragma unroll
    for (int kk = 0; kk < 2; ++kk) {
      int r = m * 16 + ln15, kc = kk * 4 + lq;
      af[kk] = *(const bf16x8*)(qtS + r * 128 + ((kc ^ (r & 7)) << 4));
    }
    f32x4 a1[4] = {};
#pragma unroll
    for (int kk = 0; kk < 2; ++kk)
#pragma unroll
      for (int n = 0; n < 4; ++n)
        a1[n] = __builtin_amdgcn_mfma_f32_16x16x32_bf16(af[kk], pf[n][kk], a1[n], 0, 0, 0);
#pragma unroll
    for (int n = 0; n < 4; ++n) {
      int f = wid * 64 + n * 16 + ln15;
      int c = f >> 3, wb = (f & 7) * 2;
#pragma unroll
      for (int j = 0; j < 4; ++j) {
        int row = m * 16 + lq * 4 + j;
        float v = a1[n][j];
        float o = v > 0.f ? v + 1.f : __expf(v);
        *(u16*)(qfS + row * 512 + ((c ^ (row & 7)) << 4) + wb) = f2bf(o);
      }
    }
  }
  __syncthreads();

  {
    int n = tid & 63, q = tid >> 6;
    const float* kp = ksum + (size_t)bh * 256;
    float s = 0.f;
#pragma unroll
    for (int c = q * 8; c < q * 8 + 8; ++c) {
      u16x8 v = *(const u16x8*)(qfS + n * 512 + ((c ^ (n & 7)) << 4));
#pragma unroll
      for (int j = 0; j < 8; ++j) s += bf2f(v[j]) * kp[c * 8 + j];
    }
    zpart[n][q] = s;
  }
  __syncthreads();
  if (tid < 64) zS[tid] = 1.f / (zpart[tid][0] + zpart[tid][1] + zpart[tid][2] + zpart[tid][3] + 1e-8f);
  __syncthreads();

  f32x4 a2[4] = {};
  const u16* kvg = kvT + (size_t)bh * 16384;
#pragma unroll
  for (int kk = 0; kk < 8; ++kk) {
    int kc = kk * 4 + lq;
    int r = wid * 16 + ln15;
    bf16x8 af = *(const bf16x8*)(qfS + r * 512 + ((kc ^ (r & 7)) << 4));
#pragma unroll
    for (int nf = 0; nf < 4; ++nf) {
      int d = nf * 16 + ln15;
      bf16x8 bv = *(const bf16x8*)(kvg + (size_t)d * 256 + kc * 8);
      a2[nf] = __builtin_amdgcn_mfma_f32_16x16x32_bf16(af, bv, a2[nf], 0, 0, 0);
    }
  }
#pragma unroll
  for (int nf = 0; nf < 4; ++nf)
#pragma unroll
    for (int j = 0; j < 4; ++j) {
      int d = nf * 16 + ln15;
      int n = wid * 16 + lq * 4 + j;
      float v = a2[nf][j] * zS[n];
      attnb[((size_t)b * 4096 + n0 + n) * 1024 + h * 64 + d] = f2bf(v);
    }
}

__global__ __launch_bounds__(256) void cast_kernel(const float* __restrict__ in, u16* __restrict__ out, int n4)
{
  int i = blockIdx.x * 256 + threadIdx.x;
  if (i >= n4) return;
  float4 v = ((const float4*)in)[i];
  u16x4 o = { f2bf(v.x), f2bf(v.y), f2bf(v.z), f2bf(v.w) };
  ((u16x4*)out)[i] = o;
}

__global__ __launch_bounds__(256) void projt_kernel(const float* __restrict__ proj, u16* __restrict__ out)
{
  int i = blockIdx.x * 256 + threadIdx.x;
  int d = i & 63, f = (i >> 6) & 255, h = i >> 14;
  out[i] = f2bf(proj[((size_t)h * 64 + d) * 256 + f]);
}

__global__ __launch_bounds__(256) void ln_kernel(const float* __restrict__ in, const float* __restrict__ gamma,
                                                 const float* __restrict__ beta, float* __restrict__ outF,
                                                 u16* __restrict__ outB)
{
  int row = blockIdx.x, tid = threadIdx.x;
  float4 v = ((const float4*)(in + (size_t)row * 1024))[tid];
  float s = v.x + v.y + v.z + v.w;
  float q = v.x * v.x + v.y * v.y + v.z * v.z + v.w * v.w;
  for (int off = 32; off; off >>= 1) { s += __shfl_down(s, off); q += __shfl_down(q, off); }
  __shared__ float rs[4], rq[4];
  int wid = tid >> 6, lane = tid & 63;
  if (!lane) { rs[wid] = s; rq[wid] = q; }
  __syncthreads();
  s = rs[0] + rs[1] + rs[2] + rs[3];
  q = rq[0] + rq[1] + rq[2] + rq[3];
  float mu = s * (1.f / 1024.f);
  float rstd = rsqrtf(q * (1.f / 1024.f) - mu * mu + 1e-5f);
  float4 g = ((const float4*)gamma)[tid];
  float4 bb = ((const float4*)beta)[tid];
  float4 o;
  o.x = (v.x - mu) * rstd * g.x + bb.x;
  o.y = (v.y - mu) * rstd * g.y + bb.y;
  o.z = (v.z - mu) * rstd * g.z + bb.z;
  o.w = (v.w - mu) * rstd * g.w + bb.w;
  ((float4*)(outF + (size_t)row * 1024))[tid] = o;
  if (outB) {
    u16x4 ob = { f2bf(o.x), f2bf(o.y), f2bf(o.z), f2bf(o.w) };
    ((u16x4*)(outB + (size_t)row * 1024))[tid] = ob;
  }
}

// ---------------------------------------------------------------------------
// Workspace. d_out doubles as scratch:
//   phase A: xb (bf16 x) in d_out[0..33.5MB)
//   phase B: kvpart f32 [bh][chunk 8][d][f] in d_out (33.5MB)
//   phase C: outproj result f32 (full overwrite) -> LN -> final
// ---------------------------------------------------------------------------
#define O_WQKVB   0L
#define O_WOUTB   6291456L
#define O_W1B     8388608L
#define O_W2B     16777216L
#define O_PROJT   25165824L
#define O_KSUM    25690112L
#define O_KSP     26804224L
#define O_KVB     27852800L
#define O_QFG     37289984L
#define O_QKVB    70844416L
#define O_ATTNB   171507712L
#define WS_NEED   205062144L

extern "C" void kernel_launch(void* const* d_in, const int* in_sizes, int n_in,
                              void* d_out, int out_size, void* d_ws, size_t ws_size,
                              hipStream_t stream)
{
  if (ws_size < (size_t)WS_NEED) return;

  const float* x     = (const float*)d_in[0];
  const float* proj  = (const float*)d_in[1];
  const float* wqkv  = (const float*)d_in[2];
  const float* wout  = (const float*)d_in[3];
  const float* bout  = (const float*)d_in[4];
  const float* gamma = (const float*)d_in[5];
  const float* beta  = (const float*)d_in[6];
  const float* w1    = (const float*)d_in[7];
  const float* b1    = (const float*)d_in[8];
  const float* w2    = (const float*)d_in[9];
  const float* b2    = (const float*)d_in[10];
  float* outp = (float*)d_out;
  char* ws = (char*)d_ws;

  u16* wqkvb  = (u16*)(ws + O_WQKVB);
  u16* woutb  = (u16*)(ws + O_WOUTB);
  u16* w1b    = (u16*)(ws + O_W1B);
  u16* w2b    = (u16*)(ws + O_W2B);
  u16* projTb = (u16*)(ws + O_PROJT);
  float* ksumf= (float*)(ws + O_KSUM);
  float* ksp  = (float*)(ws + O_KSP);
  u16* kvTb   = (u16*)(ws + O_KVB);
  u16* qkvb   = (u16*)(ws + O_QKVB);
  u16* attnb  = (u16*)(ws + O_ATTNB);
  u16* x1b    = (u16*)(ws + O_QFG);
  u16* hbu    = (u16*)(ws + O_QKVB);

  u16* xbD   = (u16*)d_out;
  float* kvp = (float*)d_out;

  cast_kernel<<<16384, 256, 0, stream>>>(x, xbD, 4194304);
  cast_kernel<<<3072, 256, 0, stream>>>(wqkv, wqkvb, 786432);
  cast_kernel<<<1024, 256, 0, stream>>>(wout, woutb, 262144);
  cast_kernel<<<4096, 256, 0, stream>>>(w1, w1b, 1048576);
  cast_kernel<<<4096, 256, 0, stream>>>(w2, w2b, 1048576);
  projt_kernel<<<1024, 256, 0, stream>>>(proj, projTb);

  gemm_nt<0><<<dim3(24, 128, 1), 256, 0, stream>>>(xbD, wqkvb, qkvb, nullptr, nullptr,
      16384, 3072, 1024, 1024, 1024, 3072, 0L, 0L, 0L, 0L, 0L, 0L, 1, 0L);

  fused_kv<<<dim3(8, 64), 256, 0, stream>>>(qkvb, projTb, kvp, ksp);
  kv_finalize<<<256, 256, 0, stream>>>(kvp, ksp, kvTb, ksumf);
  fused_attn<<<dim3(64, 64), 256, 0, stream>>>(qkvb, projTb, kvTb, ksumf, attnb);

  gemm_nt<3><<<dim3(8, 128, 1), 256, 0, stream>>>(attnb, woutb, outp, bout, x,
      16384, 1024, 1024, 1024, 1024, 1024, 0L, 0L, 0L, 0L, 0L, 0L, 1, 0L);

  ln_kernel<<<16384, 256, 0, stream>>>(outp, gamma, beta, outp, x1b);

  for (int half = 0; half < 2; ++half) {
    gemm_nt<4><<<dim3(16, 128, 1), 256, 0, stream>>>(x1b, w1b + (long)half * 2097152L, hbu,
        b1 + half * 2048, nullptr, 16384, 2048, 1024, 1024, 1024, 2048,
        0L, 0L, 0L, 0L, 0L, 0L, 1, 0L);
    if (half == 0) {
      gemm_nt<3><<<dim3(8, 128, 1), 256, 0, stream>>>(hbu, w2b + 0L, outp, b2, outp,
          16384, 1024, 2048, 2048, 4096, 1024, 0L, 0L, 0L, 0L, 0L, 0L, 1, 0L);
    } else {
      gemm_nt<5><<<dim3(8, 128, 1), 256, 0, stream>>>(hbu, w2b + 2048L, outp, nullptr, nullptr,
          16384, 1024, 2048, 2048, 4096, 1024, 0L, 0L, 0L, 0L, 0L, 0L, 1, 0L);
    }
  }

  ln_kernel<<<16384, 256, 0, stream>>>(outp, gamma, beta, outp, nullptr);
}

// Round 7
// 737.234 us; speedup vs baseline: 1.5261x; 1.1128x over previous
//
#include <hip/hip_runtime.h>
#include <math.h>

typedef unsigned short u16;
typedef __bf16 bf16x8 __attribute__((ext_vector_type(8)));
typedef float f32x4 __attribute__((ext_vector_type(4)));
typedef unsigned short u16x4 __attribute__((ext_vector_type(4)));
typedef unsigned short u16x8 __attribute__((ext_vector_type(8)));

#define DEV static __device__ __forceinline__

DEV float bf2f(u16 u) { union { unsigned int i; float f; } x; x.i = ((unsigned int)u) << 16; return x.f; }
DEV u16 f2bf(float f) { union { float f; unsigned int i; } x; x.f = f; unsigned int r = x.i + 0x7fffu + ((x.i >> 16) & 1u); return (u16)(r >> 16); }

DEV void load_lds16(const void* g, void* l) {
  __builtin_amdgcn_global_load_lds((__attribute__((address_space(1))) void*)g,
                                   (__attribute__((address_space(3))) void*)l, 16, 0, 0);
}

// MFMA quadrant macro: MH/NH literals -> all acc indices compile-time (rule #20)
#define MMAQ(AREG, BREG, MH, NH)                                                            \
  do {                                                                                      \
    __builtin_amdgcn_s_setprio(1);                                                          \
    _Pragma("unroll") for (int m_ = 0; m_ < 4; ++m_)                                        \
      _Pragma("unroll") for (int n_ = 0; n_ < 2; ++n_)                                      \
        _Pragma("unroll") for (int kk_ = 0; kk_ < 2; ++kk_)                                 \
          acc[(MH)*4 + m_][(NH)*2 + n_] = __builtin_amdgcn_mfma_f32_16x16x32_bf16(          \
              AREG[m_][kk_], BREG[n_][kk_], acc[(MH)*4 + m_][(NH)*2 + n_], 0, 0, 0);        \
    __builtin_amdgcn_s_setprio(0);                                                          \
  } while (0)

// ---------------------------------------------------------------------------
// gemm256: NT GEMM C[m,n] = sum_k A[m,k]*B[n,k], bf16 in, f32 accum.
// 256x256 tile, BK=64, 512 thr = 8 waves (2M x 4N), per-wave 128x64 out.
// 8-phase-style schedule: per K-tile 4 phases {ds_read quadrant | stage |
// s_barrier | setprio+16 MFMA+setprio | s_barrier}; all 4 half-tiles of t+1
// issued in phase 1 (issue-early), single vmcnt(0) drain in phase 4
// (drain-late). Raw s_barrier (no compiler full-drain). XOR swizzle (T2)
// source-side + read-side; T1 XCD block swizzle.
// M, N multiples of 256; K multiple of 64.
// EPI: 0 bf16 | 3 f32 v+aux0[col]+aux1[idx] | 4 bias+gelu bf16
// ---------------------------------------------------------------------------
template<int EPI>
__global__ __launch_bounds__(512, 1)
void gemm256(const u16* __restrict__ A, const u16* __restrict__ B, void* __restrict__ Cv,
             const float* __restrict__ aux0, const float* __restrict__ aux1,
             int M, int N, int K, int lda, int ldb, int ldc)
{
  __shared__ __align__(16) unsigned char smem[131072];
  const int tid = threadIdx.x;
  int bx = blockIdx.x, by = blockIdx.y;
  {
    int nwg = gridDim.x * gridDim.y;
    if ((nwg & 7) == 0) {
      int wg = by * gridDim.x + bx;
      int swz = (wg & 7) * (nwg >> 3) + (wg >> 3);
      bx = swz % gridDim.x; by = swz / gridDim.x;
    }
  }
  const int m0 = by * 256, n0 = bx * 256;
  const int wid = tid >> 6, lane = tid & 63;
  const int wr = wid >> 2, wc = wid & 3;
  const int ln15 = lane & 15, lq = lane >> 4;
  const int bhalf = wc >> 1;
  const int sRow = tid >> 3, sCh = tid & 7;   // staging: row=(i*512+tid)>>3 = i*64+sRow

  f32x4 acc[8][4] = {};
  bf16x8 aR[4][2], b0R[2][2], b1R[2][2];

  // stage one 128x64 half-tile (2 x global_load_lds / thread; LDS dst linear = tid*16)
  auto stageHalf = [&](const u16* G, int ld, int grs, int k0, int ldsoff) {
#pragma unroll
    for (int i = 0; i < 2; ++i) {
      int row = i * 64 + sRow;
      const unsigned char* src = (const unsigned char*)(G + (size_t)(grs + row) * ld + k0)
                               + ((sCh ^ (row & 7)) << 4);
      load_lds16(src, smem + ldsoff + row * 128 + sCh * 16);
    }
  };
  auto stageTile = [&](int k0, int dbuf) {
    stageHalf(A, lda, m0,       k0, (dbuf * 2 + 0) * 16384);
    stageHalf(A, lda, m0 + 128, k0, (dbuf * 2 + 1) * 16384);
    stageHalf(B, ldb, n0,       k0, 65536 + (dbuf * 2 + 0) * 16384);
    stageHalf(B, ldb, n0 + 128, k0, 65536 + (dbuf * 2 + 1) * 16384);
  };
  auto loadA = [&](int cur, int mh) {
    const unsigned char* base = smem + (cur * 2 + wr) * 16384;
#pragma unroll
    for (int m = 0; m < 4; ++m) {
      int rl = (mh * 4 + m) * 16 + ln15;
#pragma unroll
      for (int kk = 0; kk < 2; ++kk)
        aR[m][kk] = *(const bf16x8*)(base + rl * 128 + (((kk * 4 + lq) ^ (rl & 7)) << 4));
    }
  };
  auto loadB = [&](int cur, int nh, bf16x8 (&bq)[2][2]) {
    const unsigned char* base = smem + 65536 + (cur * 2 + bhalf) * 16384;
#pragma unroll
    for (int n = 0; n < 2; ++n) {
      int rb = (wc & 1) * 64 + (nh * 2 + n) * 16 + ln15;
#pragma unroll
      for (int kk = 0; kk < 2; ++kk)
        bq[n][kk] = *(const bf16x8*)(base + rb * 128 + (((kk * 4 + lq) ^ (rb & 7)) << 4));
    }
  };

  const int nkt = K >> 6;

  // prologue: stage tile 0 into dbuf 0, drain, align
  stageTile(0, 0);
  asm volatile("s_waitcnt vmcnt(0)" ::: "memory");
  __builtin_amdgcn_s_barrier();

  for (int t = 0; t < nkt; ++t) {
    const int cur = t & 1;
    const bool pf = (t + 1 < nkt);
    // ---- P1: A(mh0) + B(nh0) frags; issue ALL of tile t+1's staging ----
    loadA(cur, 0);
    loadB(cur, 0, b0R);
    if (pf) stageTile((t + 1) << 6, cur ^ 1);
    __builtin_amdgcn_s_barrier();
    MMAQ(aR, b0R, 0, 0);
    __builtin_amdgcn_s_barrier();
    // ---- P2: B(nh1) frags ----
    loadB(cur, 1, b1R);
    __builtin_amdgcn_s_barrier();
    MMAQ(aR, b1R, 0, 1);
    __builtin_amdgcn_s_barrier();
    // ---- P3: A(mh1) frags ----
    loadA(cur, 1);
    __builtin_amdgcn_s_barrier();
    MMAQ(aR, b0R, 1, 0);
    __builtin_amdgcn_s_barrier();
    // ---- P4: pure MFMA, then drain staging before buffer swap ----
    MMAQ(aR, b1R, 1, 1);
    if (pf) { asm volatile("s_waitcnt vmcnt(0)" ::: "memory"); }
    __builtin_amdgcn_s_barrier();
  }

  // ---- epilogue ----
#pragma unroll
  for (int m = 0; m < 8; ++m) {
#pragma unroll
    for (int n = 0; n < 4; ++n) {
      int col = n0 + wc * 64 + n * 16 + ln15;
#pragma unroll
      for (int j = 0; j < 4; ++j) {
        int row = m0 + wr * 128 + m * 16 + lq * 4 + j;
        float v = acc[m][n][j];
        size_t idx = (size_t)row * ldc + col;
        if (EPI == 0) {
          ((u16*)Cv)[idx] = f2bf(v);
        } else if (EPI == 3) {
          ((float*)Cv)[idx] = v + aux0[col] + aux1[idx];
        } else if (EPI == 4) {
          float g = v + aux0[col];
          float o = 0.5f * g * (1.f + erff(g * 0.70710678118f));
          ((u16*)Cv)[idx] = f2bf(o);
        }
      }
    }
  }
}

// ---------------------------------------------------------------------------
// fused_kv (proven r6): grid (8 chunks x 64 bh), software-pipelined dbuf.
// ---------------------------------------------------------------------------
__global__ __launch_bounds__(256, 2)
void fused_kv(const u16* __restrict__ qkv, const u16* __restrict__ projT,
              float* __restrict__ kvpart, float* __restrict__ ksumpart)
{
  __shared__ __align__(16) unsigned char ktS[2][8192];
  __shared__ __align__(16) unsigned char vtS[2][8192];
  __shared__ __align__(16) unsigned char kfS[32768];
  const int tid = threadIdx.x;
  const int bh = blockIdx.y, chunk = blockIdx.x;
  const int b = bh >> 4, h = bh & 15;
  const int wid = tid >> 6, lane = tid & 63;
  const int ln15 = lane & 15, lq = lane >> 4;
  const int vN = tid >> 2, vD = (tid & 3) * 16;
  const int vCn = vN >> 3, vWb = (vN & 7) * 2;

  bf16x8 pf[4][2];
#pragma unroll
  for (int m = 0; m < 4; ++m)
#pragma unroll
    for (int kk = 0; kk < 2; ++kk) {
      int f = wid * 64 + m * 16 + ln15;
      pf[m][kk] = *(const bf16x8*)(projT + (size_t)h * 16384 + (size_t)f * 64 + (kk * 4 + lq) * 8);
    }

  float ksum_r = 0.f;
  f32x4 acc2[4][4] = {};
  const int nbase = chunk * 512;

  {
    const u16* kg = qkv + ((size_t)b * 4096 + nbase) * 3072 + 1024 + h * 64;
#pragma unroll
    for (int i = 0; i < 2; ++i) {
      int c = i * 256 + tid; int r = c >> 3, ch = c & 7;
      load_lds16((const unsigned char*)(kg + (size_t)r * 3072) + ((ch ^ (r & 7)) << 4),
                 ktS[0] + r * 128 + ch * 16);
    }
    const u16* vg = qkv + ((size_t)b * 4096 + nbase + vN) * 3072 + 2048 + h * 64 + vD;
    u16x8 va = *(const u16x8*)vg;
    u16x8 vb = *(const u16x8*)(vg + 8);
#pragma unroll
    for (int j = 0; j < 8; ++j) {
      int d = vD + j;
      *(u16*)(vtS[0] + d * 128 + ((vCn ^ (d & 7)) << 4) + vWb) = va[j];
    }
#pragma unroll
    for (int j = 0; j < 8; ++j) {
      int d = vD + 8 + j;
      *(u16*)(vtS[0] + d * 128 + ((vCn ^ (d & 7)) << 4) + vWb) = vb[j];
    }
  }
  __syncthreads();

  for (int t = 0; t < 8; ++t) {
    const int cur = t & 1, nxt = cur ^ 1;
    u16x8 va, vb;
    const bool havenext = (t + 1 < 8);
    if (havenext) {
      int n1 = nbase + (t + 1) * 64;
      const u16* kg = qkv + ((size_t)b * 4096 + n1) * 3072 + 1024 + h * 64;
#pragma unroll
      for (int i = 0; i < 2; ++i) {
        int c = i * 256 + tid; int r = c >> 3, ch = c & 7;
        load_lds16((const unsigned char*)(kg + (size_t)r * 3072) + ((ch ^ (r & 7)) << 4),
                   ktS[nxt] + r * 128 + ch * 16);
      }
      const u16* vg = qkv + ((size_t)b * 4096 + n1 + vN) * 3072 + 2048 + h * 64 + vD;
      va = *(const u16x8*)vg;
      vb = *(const u16x8*)(vg + 8);
    }

    bf16x8 bvk[2][4];
#pragma unroll
    for (int kk = 0; kk < 2; ++kk)
#pragma unroll
      for (int n = 0; n < 4; ++n) {
        int r = n * 16 + ln15, kc = kk * 4 + lq;
        bvk[kk][n] = *(const bf16x8*)(ktS[cur] + r * 128 + ((kc ^ (r & 7)) << 4));
      }
#pragma unroll
    for (int m = 0; m < 4; ++m) {
      f32x4 a1[4] = {};
#pragma unroll
      for (int kk = 0; kk < 2; ++kk)
#pragma unroll
        for (int n = 0; n < 4; ++n)
          a1[n] = __builtin_amdgcn_mfma_f32_16x16x32_bf16(pf[m][kk], bvk[kk][n], a1[n], 0, 0, 0);
#pragma unroll
      for (int n = 0; n < 4; ++n) {
        int nloc = n * 16 + ln15;
        int c = nloc >> 3, wb = (nloc & 7) * 2;
#pragma unroll
        for (int j = 0; j < 4; ++j) {
          int f = wid * 64 + m * 16 + lq * 4 + j;
          float v = a1[n][j];
          float o = v > 0.f ? v + 1.f : __expf(v);
          *(u16*)(kfS + f * 128 + ((c ^ (f & 7)) << 4) + wb) = f2bf(o);
        }
      }
    }
    __syncthreads();

    {
      int f = tid;
      float s = 0.f;
#pragma unroll
      for (int c = 0; c < 8; ++c) {
        u16x8 v = *(const u16x8*)(kfS + f * 128 + ((c ^ (f & 7)) << 4));
#pragma unroll
        for (int j = 0; j < 8; ++j) s += bf2f(v[j]);
      }
      ksum_r += s;
    }
#pragma unroll
    for (int kk = 0; kk < 2; ++kk) {
      int kc = kk * 4 + lq;
      bf16x8 af[4], bv[4];
#pragma unroll
      for (int m = 0; m < 4; ++m) { int r = wid * 64 + m * 16 + ln15; af[m] = *(const bf16x8*)(kfS + r * 128 + ((kc ^ (r & 7)) << 4)); }
#pragma unroll
      for (int n = 0; n < 4; ++n) { int r = n * 16 + ln15; bv[n] = *(const bf16x8*)(vtS[cur] + r * 128 + ((kc ^ (r & 7)) << 4)); }
#pragma unroll
      for (int m = 0; m < 4; ++m)
#pragma unroll
        for (int n = 0; n < 4; ++n)
          acc2[m][n] = __builtin_amdgcn_mfma_f32_16x16x32_bf16(af[m], bv[n], acc2[m][n], 0, 0, 0);
    }
    if (havenext) {
#pragma unroll
      for (int j = 0; j < 8; ++j) {
        int d = vD + j;
        *(u16*)(vtS[nxt] + d * 128 + ((vCn ^ (d & 7)) << 4) + vWb) = va[j];
      }
#pragma unroll
      for (int j = 0; j < 8; ++j) {
        int d = vD + 8 + j;
        *(u16*)(vtS[nxt] + d * 128 + ((vCn ^ (d & 7)) << 4) + vWb) = vb[j];
      }
    }
    __syncthreads();
  }

  const size_t pbase = ((size_t)bh * 8 + chunk) * 16384;
#pragma unroll
  for (int half = 0; half < 2; ++half) {
#pragma unroll
    for (int m = 0; m < 4; ++m)
#pragma unroll
      for (int n2 = 0; n2 < 2; ++n2) {
        int n = half * 2 + n2;
        int dloc = n2 * 16 + ln15;
        int f = wid * 64 + m * 16 + lq * 4;
        *(f32x4*)(kfS + dloc * 1024 + ((f * 4) ^ ((dloc & 7) << 4))) = acc2[m][n];
      }
    __syncthreads();
#pragma unroll
    for (int k = 0; k < 8; ++k) {
      int dloc = k * 4 + wid;
      f32x4 val = *(const f32x4*)(kfS + dloc * 1024 + ((lane * 16) ^ ((dloc & 7) << 4)));
      *(f32x4*)(kvpart + pbase + (size_t)(half * 32 + dloc) * 256 + lane * 4) = val;
    }
    __syncthreads();
  }
  ksumpart[((size_t)bh * 8 + chunk) * 256 + tid] = ksum_r;
}

__global__ __launch_bounds__(256) void kv_finalize(const float* __restrict__ kvpart,
    const float* __restrict__ ksumpart, u16* __restrict__ kvT, float* __restrict__ ksum)
{
  int bx = blockIdx.x, bh = bx >> 2, dq = bx & 3, tid = threadIdx.x;
  const float* base = kvpart + (size_t)bh * 131072;
  u16* out = kvT + (size_t)bh * 16384;
#pragma unroll
  for (int k = 0; k < 16; ++k) {
    int idx = dq * 4096 + k * 256 + tid;
    float s = 0.f;
#pragma unroll
    for (int c = 0; c < 8; ++c) s += base[(size_t)c * 16384 + idx];
    out[idx] = f2bf(s);
  }
  if (dq == 0) {
    float s = 0.f;
#pragma unroll
    for (int c = 0; c < 8; ++c) s += ksumpart[((size_t)bh * 8 + c) * 256 + tid];
    ksum[(size_t)bh * 256 + tid] = s;
  }
}

__global__ __launch_bounds__(256, 3)
void fused_attn(const u16* __restrict__ qkv, const u16* __restrict__ projT,
                const u16* __restrict__ kvT, const float* __restrict__ ksum,
                u16* __restrict__ attnb)
{
  __shared__ __align__(16) unsigned char qtS[8192];
  __shared__ __align__(16) unsigned char qfS[32768];
  __shared__ float zpart[64][4];
  __shared__ float zS[64];
  const int tid = threadIdx.x;
  const int bh = blockIdx.y, nt = blockIdx.x;
  const int b = bh >> 4, h = bh & 15;
  const int wid = tid >> 6, lane = tid & 63;
  const int ln15 = lane & 15, lq = lane >> 4;
  const int n0 = nt * 64;

  bf16x8 pf[4][2];
#pragma unroll
  for (int n = 0; n < 4; ++n)
#pragma unroll
    for (int kk = 0; kk < 2; ++kk) {
      int f = wid * 64 + n * 16 + ln15;
      pf[n][kk] = *(const bf16x8*)(projT + (size_t)h * 16384 + (size_t)f * 64 + (kk * 4 + lq) * 8);
    }

  const u16* qg = qkv + ((size_t)b * 4096 + n0) * 3072 + h * 64;
#pragma unroll
  for (int i = 0; i < 2; ++i) {
    int c = i * 256 + tid; int r = c >> 3, ch = c & 7;
    load_lds16((const unsigned char*)(qg + (size_t)r * 3072) + ((ch ^ (r & 7)) << 4),
               qtS + r * 128 + ch * 16);
  }
  __syncthreads();

#pragma unroll
  for (int m = 0; m < 4; ++m) {
    bf16x8 af[2];
#pragma unroll
    for (int kk = 0; kk < 2; ++kk) {
      int r = m * 16 + ln15, kc = kk * 4 + lq;
      af[kk] = *(const bf16x8*)(qtS + r * 128 + ((kc ^ (r & 7)) << 4));
    }
    f32x4 a1[4] = {};
#pragma unroll
    for (int kk = 0; kk < 2; ++kk)
#pragma unroll
      for (int n = 0; n < 4; ++n)
        a1[n] = __builtin_amdgcn_mfma_f32_16x16x32_bf16(af[kk], pf[n][kk], a1[n], 0, 0, 0);
#pragma unroll
    for (int n = 0; n < 4; ++n) {
      int f = wid * 64 + n * 16 + ln15;
      int c = f >> 3, wb = (f & 7) * 2;
#pragma unroll
      for (int j = 0; j < 4; ++j) {
        int row = m * 16 + lq * 4 + j;
        float v = a1[n][j];
        float o = v > 0.f ? v + 1.f : __expf(v);
        *(u16*)(qfS + row * 512 + ((c ^ (row & 7)) << 4) + wb) = f2bf(o);
      }
    }
  }
  __syncthreads();

  {
    int n = tid & 63, q = tid >> 6;
    const float* kp = ksum + (size_t)bh * 256;
    float s = 0.f;
#pragma unroll
    for (int c = q * 8; c < q * 8 + 8; ++c) {
      u16x8 v = *(const u16x8*)(qfS + n * 512 + ((c ^ (n & 7)) << 4));
#pragma unroll
      for (int j = 0; j < 8; ++j) s += bf2f(v[j]) * kp[c * 8 + j];
    }
    zpart[n][q] = s;
  }
  __syncthreads();
  if (tid < 64) zS[tid] = 1.f / (zpart[tid][0] + zpart[tid][1] + zpart[tid][2] + zpart[tid][3] + 1e-8f);
  __syncthreads();

  f32x4 a2[4] = {};
  const u16* kvg = kvT + (size_t)bh * 16384;
#pragma unroll
  for (int kk = 0; kk < 8; ++kk) {
    int kc = kk * 4 + lq;
    int r = wid * 16 + ln15;
    bf16x8 af = *(const bf16x8*)(qfS + r * 512 + ((kc ^ (r & 7)) << 4));
#pragma unroll
    for (int nf = 0; nf < 4; ++nf) {
      int d = nf * 16 + ln15;
      bf16x8 bv = *(const bf16x8*)(kvg + (size_t)d * 256 + kc * 8);
      a2[nf] = __builtin_amdgcn_mfma_f32_16x16x32_bf16(af, bv, a2[nf], 0, 0, 0);
    }
  }
#pragma unroll
  for (int nf = 0; nf < 4; ++nf)
#pragma unroll
    for (int j = 0; j < 4; ++j) {
      int d = nf * 16 + ln15;
      int n = wid * 16 + lq * 4 + j;
      float v = a2[nf][j] * zS[n];
      attnb[((size_t)b * 4096 + n0 + n) * 1024 + h * 64 + d] = f2bf(v);
    }
}

__global__ __launch_bounds__(256) void cast_kernel(const float* __restrict__ in, u16* __restrict__ out, int n4)
{
  int i = blockIdx.x * 256 + threadIdx.x;
  if (i >= n4) return;
  float4 v = ((const float4*)in)[i];
  u16x4 o = { f2bf(v.x), f2bf(v.y), f2bf(v.z), f2bf(v.w) };
  ((u16x4*)out)[i] = o;
}

__global__ __launch_bounds__(256) void projt_kernel(const float* __restrict__ proj, u16* __restrict__ out)
{
  int i = blockIdx.x * 256 + threadIdx.x;
  int d = i & 63, f = (i >> 6) & 255, h = i >> 14;
  out[i] = f2bf(proj[((size_t)h * 64 + d) * 256 + f]);
}

__global__ __launch_bounds__(256) void ln_kernel(const float* __restrict__ in, const float* __restrict__ gamma,
                                                 const float* __restrict__ beta, float* __restrict__ outF,
                                                 u16* __restrict__ outB)
{
  int row = blockIdx.x, tid = threadIdx.x;
  float4 v = ((const float4*)(in + (size_t)row * 1024))[tid];
  float s = v.x + v.y + v.z + v.w;
  float q = v.x * v.x + v.y * v.y + v.z * v.z + v.w * v.w;
  for (int off = 32; off; off >>= 1) { s += __shfl_down(s, off); q += __shfl_down(q, off); }
  __shared__ float rs[4], rq[4];
  int wid = tid >> 6, lane = tid & 63;
  if (!lane) { rs[wid] = s; rq[wid] = q; }
  __syncthreads();
  s = rs[0] + rs[1] + rs[2] + rs[3];
  q = rq[0] + rq[1] + rq[2] + rq[3];
  float mu = s * (1.f / 1024.f);
  float rstd = rsqrtf(q * (1.f / 1024.f) - mu * mu + 1e-5f);
  float4 g = ((const float4*)gamma)[tid];
  float4 bb = ((const float4*)beta)[tid];
  float4 o;
  o.x = (v.x - mu) * rstd * g.x + bb.x;
  o.y = (v.y - mu) * rstd * g.y + bb.y;
  o.z = (v.z - mu) * rstd * g.z + bb.z;
  o.w = (v.w - mu) * rstd * g.w + bb.w;
  ((float4*)(outF + (size_t)row * 1024))[tid] = o;
  if (outB) {
    u16x4 ob = { f2bf(o.x), f2bf(o.y), f2bf(o.z), f2bf(o.w) };
    ((u16x4*)(outB + (size_t)row * 1024))[tid] = ob;
  }
}

// ---------------------------------------------------------------------------
// Workspace (205 MB). d_out doubles as scratch:
//   phase A: xb (bf16 x) in d_out[0..33.5MB)
//   phase B: kvpart f32 in d_out (33.5MB)
//   phase C: outproj f32 (full overwrite) -> LN -> final
// h (134MB) = ws[O_QKVB..WS_NEED) — overlays dead qkvb+attnb during MLP.
// ---------------------------------------------------------------------------
#define O_WQKVB   0L
#define O_WOUTB   6291456L
#define O_W1B     8388608L
#define O_W2B     16777216L
#define O_PROJT   25165824L
#define O_KSUM    25690112L
#define O_KSP     26804224L
#define O_KVB     27852800L
#define O_QFG     37289984L
#define O_QKVB    70844416L
#define O_ATTNB   171507712L
#define WS_NEED   205062144L

extern "C" void kernel_launch(void* const* d_in, const int* in_sizes, int n_in,
                              void* d_out, int out_size, void* d_ws, size_t ws_size,
                              hipStream_t stream)
{
  if (ws_size < (size_t)WS_NEED) return;

  const float* x     = (const float*)d_in[0];
  const float* proj  = (const float*)d_in[1];
  const float* wqkv  = (const float*)d_in[2];
  const float* wout  = (const float*)d_in[3];
  const float* bout  = (const float*)d_in[4];
  const float* gamma = (const float*)d_in[5];
  const float* beta  = (const float*)d_in[6];
  const float* w1    = (const float*)d_in[7];
  const float* b1    = (const float*)d_in[8];
  const float* w2    = (const float*)d_in[9];
  const float* b2    = (const float*)d_in[10];
  float* outp = (float*)d_out;
  char* ws = (char*)d_ws;

  u16* wqkvb  = (u16*)(ws + O_WQKVB);
  u16* woutb  = (u16*)(ws + O_WOUTB);
  u16* w1b    = (u16*)(ws + O_W1B);
  u16* w2b    = (u16*)(ws + O_W2B);
  u16* projTb = (u16*)(ws + O_PROJT);
  float* ksumf= (float*)(ws + O_KSUM);
  float* ksp  = (float*)(ws + O_KSP);
  u16* kvTb   = (u16*)(ws + O_KVB);
  u16* qkvb   = (u16*)(ws + O_QKVB);
  u16* attnb  = (u16*)(ws + O_ATTNB);
  u16* x1b    = (u16*)(ws + O_QFG);
  u16* hfull  = (u16*)(ws + O_QKVB);   // 134MB, overlays dead qkvb+attnb

  u16* xbD   = (u16*)d_out;
  float* kvp = (float*)d_out;

  cast_kernel<<<16384, 256, 0, stream>>>(x, xbD, 4194304);
  cast_kernel<<<3072, 256, 0, stream>>>(wqkv, wqkvb, 786432);
  cast_kernel<<<1024, 256, 0, stream>>>(wout, woutb, 262144);
  cast_kernel<<<4096, 256, 0, stream>>>(w1, w1b, 1048576);
  cast_kernel<<<4096, 256, 0, stream>>>(w2, w2b, 1048576);
  projt_kernel<<<1024, 256, 0, stream>>>(proj, projTb);

  // qkv = x @ w_qkv^T : M=16384, N=3072, K=1024
  gemm256<0><<<dim3(12, 64), 512, 0, stream>>>(xbD, wqkvb, qkvb, nullptr, nullptr,
      16384, 3072, 1024, 1024, 1024, 3072);

  fused_kv<<<dim3(8, 64), 256, 0, stream>>>(qkvb, projTb, kvp, ksp);
  kv_finalize<<<256, 256, 0, stream>>>(kvp, ksp, kvTb, ksumf);
  fused_attn<<<dim3(64, 64), 256, 0, stream>>>(qkvb, projTb, kvTb, ksumf, attnb);

  // t = x + attn @ w_out^T + b_out : M=16384, N=1024, K=1024 (f32 -> d_out)
  gemm256<3><<<dim3(4, 64), 512, 0, stream>>>(attnb, woutb, outp, bout, x,
      16384, 1024, 1024, 1024, 1024, 1024);

  ln_kernel<<<16384, 256, 0, stream>>>(outp, gamma, beta, outp, x1b);

  // h = gelu(x1 @ w1^T + b1) : M=16384, N=4096, K=1024
  gemm256<4><<<dim3(16, 64), 512, 0, stream>>>(x1b, w1b, hfull, b1, nullptr,
      16384, 4096, 1024, 1024, 1024, 4096);

  // y = x1 + h @ w2^T + b2 : M=16384, N=1024, K=4096 (in-place RMW on d_out)
  gemm256<3><<<dim3(4, 64), 512, 0, stream>>>(hfull, w2b, outp, b2, outp,
      16384, 1024, 4096, 4096, 4096, 1024);

  ln_kernel<<<16384, 256, 0, stream>>>(outp, gamma, beta, outp, nullptr);
}

// Round 8
// 724.311 us; speedup vs baseline: 1.5533x; 1.0178x over previous
//
#include <hip/hip_runtime.h>
#include <math.h>

typedef unsigned short u16;
typedef unsigned char u8;
typedef __bf16 bf16x8 __attribute__((ext_vector_type(8)));
typedef float f32x4 __attribute__((ext_vector_type(4)));
typedef unsigned short u16x4 __attribute__((ext_vector_type(4)));
typedef unsigned short u16x8 __attribute__((ext_vector_type(8)));

#define DEV static __device__ __forceinline__

DEV float bf2f(u16 u) { union { unsigned int i; float f; } x; x.i = ((unsigned int)u) << 16; return x.f; }
DEV u16 f2bf(float f) { union { float f; unsigned int i; } x; x.f = f; unsigned int r = x.i + 0x7fffu + ((x.i >> 16) & 1u); return (u16)(r >> 16); }

DEV void load_lds16(const void* g, void* l) {
  __builtin_amdgcn_global_load_lds((__attribute__((address_space(1))) void*)g,
                                   (__attribute__((address_space(3))) void*)l, 16, 0, 0);
}

// MFMA quadrant: MH/NH literals -> all acc indices compile-time (rule #20)
#define MMAQ(AREG, BREG, MH, NH)                                                            \
  do {                                                                                      \
    __builtin_amdgcn_s_setprio(1);                                                          \
    _Pragma("unroll") for (int m_ = 0; m_ < 4; ++m_)                                        \
      _Pragma("unroll") for (int n_ = 0; n_ < 2; ++n_)                                      \
        _Pragma("unroll") for (int kk_ = 0; kk_ < 2; ++kk_)                                 \
          acc[(MH)*4 + m_][(NH)*2 + n_] = __builtin_amdgcn_mfma_f32_16x16x32_bf16(          \
              AREG[m_][kk_], BREG[n_][kk_], acc[(MH)*4 + m_][(NH)*2 + n_], 0, 0, 0);        \
    __builtin_amdgcn_s_setprio(0);                                                          \
  } while (0)

// ---------------------------------------------------------------------------
// gemm256 v2: NT GEMM C[m,n]=sum_k A[m,k]*B[n,k], 256x256 tile, BK=64,
// 512 thr = 8 waves (2M x 4N), per-wave 128x64 out, 128KB LDS (2 dbuf).
// T4 counted vmcnt: tile t's P4 stages tile t+2 into buf[cur] (whose last
// ds_read completed at P3, barrier-proven); drain vmcnt(8) -> tile t+1's
// loads (staged a full tile earlier) are landed; never vmcnt(0) until tail.
// HK-style addressing: per-thread swizzle is invariant (row&7 == ln15&7), so
// ds_read = 4 register bases (XOR 32768/tile) + compile-time immediates;
// staging = 8 pointers advancing +128B/tile. T2 XOR swizzle both-sides.
// M,N multiples of 256; K multiple of 64, K/64 >= 2.
// EPI: 0 bf16 | 3 f32 v+aux0[col]+aux1[idx] | 4 bias+gelu bf16
// ---------------------------------------------------------------------------
template<int EPI>
__global__ __launch_bounds__(512, 1)
void gemm256(const u16* __restrict__ A, const u16* __restrict__ B, void* __restrict__ Cv,
             const float* __restrict__ aux0, const float* __restrict__ aux1,
             int M, int N, int K, int lda, int ldb, int ldc)
{
  __shared__ __align__(16) unsigned char smem[131072];
  const int tid = threadIdx.x;
  int bx = blockIdx.x, by = blockIdx.y;
  {
    int nwg = gridDim.x * gridDim.y;
    if ((nwg & 7) == 0) {
      int wg = by * gridDim.x + bx;
      int swz = (wg & 7) * (nwg >> 3) + (wg >> 3);
      bx = swz % gridDim.x; by = swz / gridDim.x;
    }
  }
  const int m0 = by * 256, n0 = bx * 256;
  const int wid = tid >> 6, lane = tid & 63;
  const int wr = wid >> 2, wc = wid & 3;
  const int ln15 = lane & 15, lq = lane >> 4;
  const int bhalf = wc >> 1;
  const int sRow = tid >> 3, sCh = tid & 7;

  f32x4 acc[8][4] = {};
  bf16x8 aR[4][2], b0R[2][2], b1R[2][2];

  // ---- precomputed staging pointers (advance +128B per staged tile) ----
  const u8* gsrc[8];
  unsigned ldst[8];
  {
    const int r0 = sRow, r1 = sRow + 64;
    const unsigned sc0 = (unsigned)((sCh ^ (r0 & 7)) << 4);
    const unsigned sc1 = (unsigned)((sCh ^ (r1 & 7)) << 4);
    gsrc[0] = (const u8*)(A + (size_t)(m0 + r0) * lda) + sc0;
    gsrc[1] = (const u8*)(A + (size_t)(m0 + r1) * lda) + sc1;
    gsrc[2] = (const u8*)(A + (size_t)(m0 + 128 + r0) * lda) + sc0;
    gsrc[3] = (const u8*)(A + (size_t)(m0 + 128 + r1) * lda) + sc1;
    gsrc[4] = (const u8*)(B + (size_t)(n0 + r0) * ldb) + sc0;
    gsrc[5] = (const u8*)(B + (size_t)(n0 + r1) * ldb) + sc1;
    gsrc[6] = (const u8*)(B + (size_t)(n0 + 128 + r0) * ldb) + sc0;
    gsrc[7] = (const u8*)(B + (size_t)(n0 + 128 + r1) * ldb) + sc1;
    const unsigned base = (unsigned)(sRow * 128 + sCh * 16);
    ldst[0] = base;            ldst[1] = base + 8192;
    ldst[2] = base + 16384;    ldst[3] = base + 16384 + 8192;
    ldst[4] = base + 65536;    ldst[5] = base + 65536 + 8192;
    ldst[6] = base + 81920;    ldst[7] = base + 81920 + 8192;
  }
#define STAGE(BUFSEL)                                                      \
  do {                                                                     \
    const unsigned bo_ = (unsigned)(BUFSEL) << 15;                         \
    _Pragma("unroll") for (int j_ = 0; j_ < 8; ++j_)                       \
      load_lds16(gsrc[j_], smem + (ldst[j_] + bo_));                       \
  } while (0)
#define ADV()                                                              \
  do { _Pragma("unroll") for (int j_ = 0; j_ < 8; ++j_) gsrc[j_] += 128; } while (0)

  // ---- precomputed ds_read bases (buf0); XOR 32768 flips buffer ----
  const unsigned swk0 = (unsigned)(((0 * 4 + lq) ^ (ln15 & 7)) << 4);
  const unsigned swk1 = (unsigned)(((1 * 4 + lq) ^ (ln15 & 7)) << 4);
  unsigned aOff0 = (unsigned)(wr * 16384 + ln15 * 128) + swk0;
  unsigned aOff1 = (unsigned)(wr * 16384 + ln15 * 128) + swk1;
  unsigned bOff0 = (unsigned)(65536 + bhalf * 16384 + ((wc & 1) * 64 + ln15) * 128) + swk0;
  unsigned bOff1 = (unsigned)(65536 + bhalf * 16384 + ((wc & 1) * 64 + ln15) * 128) + swk1;
#define LDA(MH)                                                                     \
  do { _Pragma("unroll") for (int m_ = 0; m_ < 4; ++m_) {                           \
    aR[m_][0] = *(const bf16x8*)(smem + aOff0 + ((MH) * 8192 + m_ * 2048));         \
    aR[m_][1] = *(const bf16x8*)(smem + aOff1 + ((MH) * 8192 + m_ * 2048));         \
  } } while (0)
#define LDB(NH, BQ)                                                                 \
  do { _Pragma("unroll") for (int n_ = 0; n_ < 2; ++n_) {                           \
    BQ[n_][0] = *(const bf16x8*)(smem + bOff0 + ((NH) * 4096 + n_ * 2048));         \
    BQ[n_][1] = *(const bf16x8*)(smem + bOff1 + ((NH) * 4096 + n_ * 2048));         \
  } } while (0)

  const int nkt = K >> 6;

  // ---- prologue: stage tiles 0 and 1; wait tile 0 landed ----
  STAGE(0); ADV();
  STAGE(1); ADV();
  asm volatile("s_waitcnt vmcnt(8)" ::: "memory");
  __builtin_amdgcn_s_barrier();

  for (int t = 0; t < nkt; ++t) {
    // P1
    LDA(0); LDB(0, b0R);
    __builtin_amdgcn_s_barrier();
    MMAQ(aR, b0R, 0, 0);
    __builtin_amdgcn_s_barrier();
    // P2
    LDB(1, b1R);
    __builtin_amdgcn_s_barrier();
    MMAQ(aR, b1R, 0, 1);
    __builtin_amdgcn_s_barrier();
    // P3
    LDA(1);
    __builtin_amdgcn_s_barrier();
    MMAQ(aR, b0R, 1, 0);
    __builtin_amdgcn_s_barrier();
    // P4: stage t+2 into buf[cur] (reads of cur done at P3), counted drain
    const bool pf2 = (t + 2 < nkt);
    if (pf2) { STAGE(t & 1); ADV(); }
    MMAQ(aR, b1R, 1, 1);
    if (pf2) asm volatile("s_waitcnt vmcnt(8)" ::: "memory");
    else     asm volatile("s_waitcnt vmcnt(0)" ::: "memory");
    __builtin_amdgcn_s_barrier();
    aOff0 ^= 32768; aOff1 ^= 32768; bOff0 ^= 32768; bOff1 ^= 32768;
  }

  // ---- epilogue ----
#pragma unroll
  for (int m = 0; m < 8; ++m) {
#pragma unroll
    for (int n = 0; n < 4; ++n) {
      int col = n0 + wc * 64 + n * 16 + ln15;
#pragma unroll
      for (int j = 0; j < 4; ++j) {
        int row = m0 + wr * 128 + m * 16 + lq * 4 + j;
        float v = acc[m][n][j];
        size_t idx = (size_t)row * ldc + col;
        if (EPI == 0) {
          ((u16*)Cv)[idx] = f2bf(v);
        } else if (EPI == 3) {
          ((float*)Cv)[idx] = v + aux0[col] + aux1[idx];
        } else if (EPI == 4) {
          float g = v + aux0[col];
          float o = 0.5f * g * (1.f + erff(g * 0.70710678118f));
          ((u16*)Cv)[idx] = f2bf(o);
        }
      }
    }
  }
#undef STAGE
#undef ADV
#undef LDA
#undef LDB
}

// ---------------------------------------------------------------------------
// fused_kv (proven r6): grid (8 chunks x 64 bh), software-pipelined dbuf.
// ---------------------------------------------------------------------------
__global__ __launch_bounds__(256, 2)
void fused_kv(const u16* __restrict__ qkv, const u16* __restrict__ projT,
              float* __restrict__ kvpart, float* __restrict__ ksumpart)
{
  __shared__ __align__(16) unsigned char ktS[2][8192];
  __shared__ __align__(16) unsigned char vtS[2][8192];
  __shared__ __align__(16) unsigned char kfS[32768];
  const int tid = threadIdx.x;
  const int bh = blockIdx.y, chunk = blockIdx.x;
  const int b = bh >> 4, h = bh & 15;
  const int wid = tid >> 6, lane = tid & 63;
  const int ln15 = lane & 15, lq = lane >> 4;
  const int vN = tid >> 2, vD = (tid & 3) * 16;
  const int vCn = vN >> 3, vWb = (vN & 7) * 2;

  bf16x8 pf[4][2];
#pragma unroll
  for (int m = 0; m < 4; ++m)
#pragma unroll
    for (int kk = 0; kk < 2; ++kk) {
      int f = wid * 64 + m * 16 + ln15;
      pf[m][kk] = *(const bf16x8*)(projT + (size_t)h * 16384 + (size_t)f * 64 + (kk * 4 + lq) * 8);
    }

  float ksum_r = 0.f;
  f32x4 acc2[4][4] = {};
  const int nbase = chunk * 512;

  {
    const u16* kg = qkv + ((size_t)b * 4096 + nbase) * 3072 + 1024 + h * 64;
#pragma unroll
    for (int i = 0; i < 2; ++i) {
      int c = i * 256 + tid; int r = c >> 3, ch = c & 7;
      load_lds16((const unsigned char*)(kg + (size_t)r * 3072) + ((ch ^ (r & 7)) << 4),
                 ktS[0] + r * 128 + ch * 16);
    }
    const u16* vg = qkv + ((size_t)b * 4096 + nbase + vN) * 3072 + 2048 + h * 64 + vD;
    u16x8 va = *(const u16x8*)vg;
    u16x8 vb = *(const u16x8*)(vg + 8);
#pragma unroll
    for (int j = 0; j < 8; ++j) {
      int d = vD + j;
      *(u16*)(vtS[0] + d * 128 + ((vCn ^ (d & 7)) << 4) + vWb) = va[j];
    }
#pragma unroll
    for (int j = 0; j < 8; ++j) {
      int d = vD + 8 + j;
      *(u16*)(vtS[0] + d * 128 + ((vCn ^ (d & 7)) << 4) + vWb) = vb[j];
    }
  }
  __syncthreads();

  for (int t = 0; t < 8; ++t) {
    const int cur = t & 1, nxt = cur ^ 1;
    u16x8 va, vb;
    const bool havenext = (t + 1 < 8);
    if (havenext) {
      int n1 = nbase + (t + 1) * 64;
      const u16* kg = qkv + ((size_t)b * 4096 + n1) * 3072 + 1024 + h * 64;
#pragma unroll
      for (int i = 0; i < 2; ++i) {
        int c = i * 256 + tid; int r = c >> 3, ch = c & 7;
        load_lds16((const unsigned char*)(kg + (size_t)r * 3072) + ((ch ^ (r & 7)) << 4),
                   ktS[nxt] + r * 128 + ch * 16);
      }
      const u16* vg = qkv + ((size_t)b * 4096 + n1 + vN) * 3072 + 2048 + h * 64 + vD;
      va = *(const u16x8*)vg;
      vb = *(const u16x8*)(vg + 8);
    }

    bf16x8 bvk[2][4];
#pragma unroll
    for (int kk = 0; kk < 2; ++kk)
#pragma unroll
      for (int n = 0; n < 4; ++n) {
        int r = n * 16 + ln15, kc = kk * 4 + lq;
        bvk[kk][n] = *(const bf16x8*)(ktS[cur] + r * 128 + ((kc ^ (r & 7)) << 4));
      }
#pragma unroll
    for (int m = 0; m < 4; ++m) {
      f32x4 a1[4] = {};
#pragma unroll
      for (int kk = 0; kk < 2; ++kk)
#pragma unroll
        for (int n = 0; n < 4; ++n)
          a1[n] = __builtin_amdgcn_mfma_f32_16x16x32_bf16(pf[m][kk], bvk[kk][n], a1[n], 0, 0, 0);
#pragma unroll
      for (int n = 0; n < 4; ++n) {
        int nloc = n * 16 + ln15;
        int c = nloc >> 3, wb = (nloc & 7) * 2;
#pragma unroll
        for (int j = 0; j < 4; ++j) {
          int f = wid * 64 + m * 16 + lq * 4 + j;
          float v = a1[n][j];
          float o = v > 0.f ? v + 1.f : __expf(v);
          *(u16*)(kfS + f * 128 + ((c ^ (f & 7)) << 4) + wb) = f2bf(o);
        }
      }
    }
    __syncthreads();

    {
      int f = tid;
      float s = 0.f;
#pragma unroll
      for (int c = 0; c < 8; ++c) {
        u16x8 v = *(const u16x8*)(kfS + f * 128 + ((c ^ (f & 7)) << 4));
#pragma unroll
        for (int j = 0; j < 8; ++j) s += bf2f(v[j]);
      }
      ksum_r += s;
    }
#pragma unroll
    for (int kk = 0; kk < 2; ++kk) {
      int kc = kk * 4 + lq;
      bf16x8 af[4], bv[4];
#pragma unroll
      for (int m = 0; m < 4; ++m) { int r = wid * 64 + m * 16 + ln15; af[m] = *(const bf16x8*)(kfS + r * 128 + ((kc ^ (r & 7)) << 4)); }
#pragma unroll
      for (int n = 0; n < 4; ++n) { int r = n * 16 + ln15; bv[n] = *(const bf16x8*)(vtS[cur] + r * 128 + ((kc ^ (r & 7)) << 4)); }
#pragma unroll
      for (int m = 0; m < 4; ++m)
#pragma unroll
        for (int n = 0; n < 4; ++n)
          acc2[m][n] = __builtin_amdgcn_mfma_f32_16x16x32_bf16(af[m], bv[n], acc2[m][n], 0, 0, 0);
    }
    if (havenext) {
#pragma unroll
      for (int j = 0; j < 8; ++j) {
        int d = vD + j;
        *(u16*)(vtS[nxt] + d * 128 + ((vCn ^ (d & 7)) << 4) + vWb) = va[j];
      }
#pragma unroll
      for (int j = 0; j < 8; ++j) {
        int d = vD + 8 + j;
        *(u16*)(vtS[nxt] + d * 128 + ((vCn ^ (d & 7)) << 4) + vWb) = vb[j];
      }
    }
    __syncthreads();
  }

  const size_t pbase = ((size_t)bh * 8 + chunk) * 16384;
#pragma unroll
  for (int half = 0; half < 2; ++half) {
#pragma unroll
    for (int m = 0; m < 4; ++m)
#pragma unroll
      for (int n2 = 0; n2 < 2; ++n2) {
        int n = half * 2 + n2;
        int dloc = n2 * 16 + ln15;
        int f = wid * 64 + m * 16 + lq * 4;
        *(f32x4*)(kfS + dloc * 1024 + ((f * 4) ^ ((dloc & 7) << 4))) = acc2[m][n];
      }
    __syncthreads();
#pragma unroll
    for (int k = 0; k < 8; ++k) {
      int dloc = k * 4 + wid;
      f32x4 val = *(const f32x4*)(kfS + dloc * 1024 + ((lane * 16) ^ ((dloc & 7) << 4)));
      *(f32x4*)(kvpart + pbase + (size_t)(half * 32 + dloc) * 256 + lane * 4) = val;
    }
    __syncthreads();
  }
  ksumpart[((size_t)bh * 8 + chunk) * 256 + tid] = ksum_r;
}

__global__ __launch_bounds__(256) void kv_finalize(const float* __restrict__ kvpart,
    const float* __restrict__ ksumpart, u16* __restrict__ kvT, float* __restrict__ ksum)
{
  int bx = blockIdx.x, bh = bx >> 2, dq = bx & 3, tid = threadIdx.x;
  const float* base = kvpart + (size_t)bh * 131072;
  u16* out = kvT + (size_t)bh * 16384;
#pragma unroll
  for (int k = 0; k < 16; ++k) {
    int idx = dq * 4096 + k * 256 + tid;
    float s = 0.f;
#pragma unroll
    for (int c = 0; c < 8; ++c) s += base[(size_t)c * 16384 + idx];
    out[idx] = f2bf(s);
  }
  if (dq == 0) {
    float s = 0.f;
#pragma unroll
    for (int c = 0; c < 8; ++c) s += ksumpart[((size_t)bh * 8 + c) * 256 + tid];
    ksum[(size_t)bh * 256 + tid] = s;
  }
}

__global__ __launch_bounds__(256, 3)
void fused_attn(const u16* __restrict__ qkv, const u16* __restrict__ projT,
                const u16* __restrict__ kvT, const float* __restrict__ ksum,
                u16* __restrict__ attnb)
{
  __shared__ __align__(16) unsigned char qtS[8192];
  __shared__ __align__(16) unsigned char qfS[32768];
  __shared__ float zpart[64][4];
  __shared__ float zS[64];
  const int tid = threadIdx.x;
  const int bh = blockIdx.y, nt = blockIdx.x;
  const int b = bh >> 4, h = bh & 15;
  const int wid = tid >> 6, lane = tid & 63;
  const int ln15 = lane & 15, lq = lane >> 4;
  const int n0 = nt * 64;

  bf16x8 pf[4][2];
#pragma unroll
  for (int n = 0; n < 4; ++n)
#pragma unroll
    for (int kk = 0; kk < 2; ++kk) {
      int f = wid * 64 + n * 16 + ln15;
      pf[n][kk] = *(const bf16x8*)(projT + (size_t)h * 16384 + (size_t)f * 64 + (kk * 4 + lq) * 8);
    }

  const u16* qg = qkv + ((size_t)b * 4096 + n0) * 3072 + h * 64;
#pragma unroll
  for (int i = 0; i < 2; ++i) {
    int c = i * 256 + tid; int r = c >> 3, ch = c & 7;
    load_lds16((const unsigned char*)(qg + (size_t)r * 3072) + ((ch ^ (r & 7)) << 4),
               qtS + r * 128 + ch * 16);
  }
  __syncthreads();

#pragma unroll
  for (int m = 0; m < 4; ++m) {
    bf16x8 af[2];
#pragma unroll
    for (int kk = 0; kk < 2; ++kk) {
      int r = m * 16 + ln15, kc = kk * 4 + lq;
      af[kk] = *(const bf16x8*)(qtS + r * 128 + ((kc ^ (r & 7)) << 4));
    }
    f32x4 a1[4] = {};
#pragma unroll
    for (int kk = 0; kk < 2; ++kk)
#pragma unroll
      for (int n = 0; n < 4; ++n)
        a1[n] = __builtin_amdgcn_mfma_f32_16x16x32_bf16(af[kk], pf[n][kk], a1[n], 0, 0, 0);
#pragma unroll
    for (int n = 0; n < 4; ++n) {
      int f = wid * 64 + n * 16 + ln15;
      int c = f >> 3, wb = (f & 7) * 2;
#pragma unroll
      for (int j = 0; j < 4; ++j) {
        int row = m * 16 + lq * 4 + j;
        float v = a1[n][j];
        float o = v > 0.f ? v + 1.f : __expf(v);
        *(u16*)(qfS + row * 512 + ((c ^ (row & 7)) << 4) + wb) = f2bf(o);
      }
    }
  }
  __syncthreads();

  {
    int n = tid & 63, q = tid >> 6;
    const float* kp = ksum + (size_t)bh * 256;
    float s = 0.f;
#pragma unroll
    for (int c = q * 8; c < q * 8 + 8; ++c) {
      u16x8 v = *(const u16x8*)(qfS + n * 512 + ((c ^ (n & 7)) << 4));
#pragma unroll
      for (int j = 0; j < 8; ++j) s += bf2f(v[j]) * kp[c * 8 + j];
    }
    zpart[n][q] = s;
  }
  __syncthreads();
  if (tid < 64) zS[tid] = 1.f / (zpart[tid][0] + zpart[tid][1] + zpart[tid][2] + zpart[tid][3] + 1e-8f);
  __syncthreads();

  f32x4 a2[4] = {};
  const u16* kvg = kvT + (size_t)bh * 16384;
#pragma unroll
  for (int kk = 0; kk < 8; ++kk) {
    int kc = kk * 4 + lq;
    int r = wid * 16 + ln15;
    bf16x8 af = *(const bf16x8*)(qfS + r * 512 + ((kc ^ (r & 7)) << 4));
#pragma unroll
    for (int nf = 0; nf < 4; ++nf) {
      int d = nf * 16 + ln15;
      bf16x8 bv = *(const bf16x8*)(kvg + (size_t)d * 256 + kc * 8);
      a2[nf] = __builtin_amdgcn_mfma_f32_16x16x32_bf16(af, bv, a2[nf], 0, 0, 0);
    }
  }
#pragma unroll
  for (int nf = 0; nf < 4; ++nf)
#pragma unroll
    for (int j = 0; j < 4; ++j) {
      int d = nf * 16 + ln15;
      int n = wid * 16 + lq * 4 + j;
      float v = a2[nf][j] * zS[n];
      attnb[((size_t)b * 4096 + n0 + n) * 1024 + h * 64 + d] = f2bf(v);
    }
}

__global__ __launch_bounds__(256) void cast_kernel(const float* __restrict__ in, u16* __restrict__ out, int n4)
{
  int i = blockIdx.x * 256 + threadIdx.x;
  if (i >= n4) return;
  float4 v = ((const float4*)in)[i];
  u16x4 o = { f2bf(v.x), f2bf(v.y), f2bf(v.z), f2bf(v.w) };
  ((u16x4*)out)[i] = o;
}

__global__ __launch_bounds__(256) void projt_kernel(const float* __restrict__ proj, u16* __restrict__ out)
{
  int i = blockIdx.x * 256 + threadIdx.x;
  int d = i & 63, f = (i >> 6) & 255, h = i >> 14;
  out[i] = f2bf(proj[((size_t)h * 64 + d) * 256 + f]);
}

__global__ __launch_bounds__(256) void ln_kernel(const float* __restrict__ in, const float* __restrict__ gamma,
                                                 const float* __restrict__ beta, float* __restrict__ outF,
                                                 u16* __restrict__ outB)
{
  int row = blockIdx.x, tid = threadIdx.x;
  float4 v = ((const float4*)(in + (size_t)row * 1024))[tid];
  float s = v.x + v.y + v.z + v.w;
  float q = v.x * v.x + v.y * v.y + v.z * v.z + v.w * v.w;
  for (int off = 32; off; off >>= 1) { s += __shfl_down(s, off); q += __shfl_down(q, off); }
  __shared__ float rs[4], rq[4];
  int wid = tid >> 6, lane = tid & 63;
  if (!lane) { rs[wid] = s; rq[wid] = q; }
  __syncthreads();
  s = rs[0] + rs[1] + rs[2] + rs[3];
  q = rq[0] + rq[1] + rq[2] + rq[3];
  float mu = s * (1.f / 1024.f);
  float rstd = rsqrtf(q * (1.f / 1024.f) - mu * mu + 1e-5f);
  float4 g = ((const float4*)gamma)[tid];
  float4 bb = ((const float4*)beta)[tid];
  float4 o;
  o.x = (v.x - mu) * rstd * g.x + bb.x;
  o.y = (v.y - mu) * rstd * g.y + bb.y;
  o.z = (v.z - mu) * rstd * g.z + bb.z;
  o.w = (v.w - mu) * rstd * g.w + bb.w;
  ((float4*)(outF + (size_t)row * 1024))[tid] = o;
  if (outB) {
    u16x4 ob = { f2bf(o.x), f2bf(o.y), f2bf(o.z), f2bf(o.w) };
    ((u16x4*)(outB + (size_t)row * 1024))[tid] = ob;
  }
}

// ---------------------------------------------------------------------------
// Workspace (205 MB). d_out doubles as scratch:
//   phase A: xb (bf16 x) in d_out[0..33.5MB)
//   phase B: kvpart f32 in d_out (33.5MB)
//   phase C: outproj f32 (full overwrite) -> LN -> final
// h (134MB) overlays dead qkvb+attnb during MLP.
// ---------------------------------------------------------------------------
#define O_WQKVB   0L
#define O_WOUTB   6291456L
#define O_W1B     8388608L
#define O_W2B     16777216L
#define O_PROJT   25165824L
#define O_KSUM    25690112L
#define O_KSP     26804224L
#define O_KVB     27852800L
#define O_QFG     37289984L
#define O_QKVB    70844416L
#define O_ATTNB   171507712L
#define WS_NEED   205062144L

extern "C" void kernel_launch(void* const* d_in, const int* in_sizes, int n_in,
                              void* d_out, int out_size, void* d_ws, size_t ws_size,
                              hipStream_t stream)
{
  if (ws_size < (size_t)WS_NEED) return;

  const float* x     = (const float*)d_in[0];
  const float* proj  = (const float*)d_in[1];
  const float* wqkv  = (const float*)d_in[2];
  const float* wout  = (const float*)d_in[3];
  const float* bout  = (const float*)d_in[4];
  const float* gamma = (const float*)d_in[5];
  const float* beta  = (const float*)d_in[6];
  const float* w1    = (const float*)d_in[7];
  const float* b1    = (const float*)d_in[8];
  const float* w2    = (const float*)d_in[9];
  const float* b2    = (const float*)d_in[10];
  float* outp = (float*)d_out;
  char* ws = (char*)d_ws;

  u16* wqkvb  = (u16*)(ws + O_WQKVB);
  u16* woutb  = (u16*)(ws + O_WOUTB);
  u16* w1b    = (u16*)(ws + O_W1B);
  u16* w2b    = (u16*)(ws + O_W2B);
  u16* projTb = (u16*)(ws + O_PROJT);
  float* ksumf= (float*)(ws + O_KSUM);
  float* ksp  = (float*)(ws + O_KSP);
  u16* kvTb   = (u16*)(ws + O_KVB);
  u16* qkvb   = (u16*)(ws + O_QKVB);
  u16* attnb  = (u16*)(ws + O_ATTNB);
  u16* x1b    = (u16*)(ws + O_QFG);
  u16* hfull  = (u16*)(ws + O_QKVB);

  u16* xbD   = (u16*)d_out;
  float* kvp = (float*)d_out;

  cast_kernel<<<16384, 256, 0, stream>>>(x, xbD, 4194304);
  cast_kernel<<<3072, 256, 0, stream>>>(wqkv, wqkvb, 786432);
  cast_kernel<<<1024, 256, 0, stream>>>(wout, woutb, 262144);
  cast_kernel<<<4096, 256, 0, stream>>>(w1, w1b, 1048576);
  cast_kernel<<<4096, 256, 0, stream>>>(w2, w2b, 1048576);
  projt_kernel<<<1024, 256, 0, stream>>>(proj, projTb);

  // qkv = x @ w_qkv^T : M=16384, N=3072, K=1024
  gemm256<0><<<dim3(12, 64), 512, 0, stream>>>(xbD, wqkvb, qkvb, nullptr, nullptr,
      16384, 3072, 1024, 1024, 1024, 3072);

  fused_kv<<<dim3(8, 64), 256, 0, stream>>>(qkvb, projTb, kvp, ksp);
  kv_finalize<<<256, 256, 0, stream>>>(kvp, ksp, kvTb, ksumf);
  fused_attn<<<dim3(64, 64), 256, 0, stream>>>(qkvb, projTb, kvTb, ksumf, attnb);

  // t = x + attn @ w_out^T + b_out : M=16384, N=1024, K=1024 (f32 -> d_out)
  gemm256<3><<<dim3(4, 64), 512, 0, stream>>>(attnb, woutb, outp, bout, x,
      16384, 1024, 1024, 1024, 1024, 1024);

  ln_kernel<<<16384, 256, 0, stream>>>(outp, gamma, beta, outp, x1b);

  // h = gelu(x1 @ w1^T + b1) : M=16384, N=4096, K=1024
  gemm256<4><<<dim3(16, 64), 512, 0, stream>>>(x1b, w1b, hfull, b1, nullptr,
      16384, 4096, 1024, 1024, 1024, 4096);

  // y = x1 + h @ w2^T + b2 : M=16384, N=1024, K=4096 (in-place RMW on d_out)
  gemm256<3><<<dim3(4, 64), 512, 0, stream>>>(hfull, w2b, outp, b2, outp,
      16384, 1024, 4096, 4096, 4096, 1024);

  ln_kernel<<<16384, 256, 0, stream>>>(outp, gamma, beta, outp, nullptr);
}

// Round 9
// 696.741 us; speedup vs baseline: 1.6148x; 1.0396x over previous
//
#include <hip/hip_runtime.h>
#include <math.h>

typedef unsigned short u16;
typedef __bf16 bf16x8 __attribute__((ext_vector_type(8)));
typedef float f32x4 __attribute__((ext_vector_type(4)));
typedef unsigned short u16x4 __attribute__((ext_vector_type(4)));
typedef unsigned short u16x8 __attribute__((ext_vector_type(8)));

#define DEV static __device__ __forceinline__

DEV float bf2f(u16 u) { union { unsigned int i; float f; } x; x.i = ((unsigned int)u) << 16; return x.f; }
DEV u16 f2bf(float f) { union { float f; unsigned int i; } x; x.f = f; unsigned int r = x.i + 0x7fffu + ((x.i >> 16) & 1u); return (u16)(r >> 16); }

DEV void load_lds16(const void* g, void* l) {
  __builtin_amdgcn_global_load_lds((__attribute__((address_space(1))) void*)g,
                                   (__attribute__((address_space(3))) void*)l, 16, 0, 0);
}

// sigmoid-form tanh-GELU: 0.5*g*(1+tanh(0.79788456*(g+0.044715 g^3)))
//                       = g / (1 + exp(-2t)).  |err vs exact erf-gelu| <= ~3e-3.
DEV float gelu_tanh(float g) {
  float t = 0.7978845608f * g * (1.f + 0.044715f * g * g);
  return g / (1.f + __expf(-2.f * t));
}

// ---------------------------------------------------------------------------
// Generic NT GEMM (proven r2-r6): C[m,n]=sum_k A[m,k]*B[n,k], 128x128 tile,
// BK=64, 4 waves, MFMA 16x16x32, XOR swizzle both-sides, T1 XCD swizzle.
// EPI: 0 bf16 | 3 f32 v+aux0[col]+aux1f32[idx] | 4 bias+gelu(tanh) bf16 |
//      7 f32 v+aux0[col]+bf16aux1[idx]
// ---------------------------------------------------------------------------
template<int EPI>
__global__ __launch_bounds__(256, 2)
void gemm_nt(const u16* __restrict__ A, const u16* __restrict__ B, void* __restrict__ Cv,
             const float* __restrict__ aux0, const void* __restrict__ aux1,
             int M, int N, int K, int lda, int ldb, int ldc)
{
  __shared__ __align__(16) unsigned char smem[32768];
  const int tid = threadIdx.x;
  int bx = blockIdx.x, by = blockIdx.y;
  {
    int nwg = gridDim.x * gridDim.y;
    if ((nwg & 7) == 0) {
      int wg = by * gridDim.x + bx;
      int swz = (wg & 7) * (nwg >> 3) + (wg >> 3);
      bx = swz % gridDim.x; by = swz / gridDim.x;
    }
  }
  const int m0 = by * 128, n0 = bx * 128;
  const int wid = tid >> 6, lane = tid & 63;
  const int wr = wid >> 1, wc = wid & 1;
  const int ln15 = lane & 15, lq = lane >> 4;
  const int srow = tid >> 3, sch = tid & 7;

  f32x4 acc[4][4] = {};

  for (int k0 = 0; k0 < K; k0 += 64) {
#pragma unroll
    for (int i = 0; i < 4; ++i) {
      int r = i * 32 + srow;
      const unsigned char* src = (const unsigned char*)(A + (size_t)(m0 + r) * lda + k0) + ((sch ^ (r & 7)) << 4);
      load_lds16(src, smem + r * 128 + (sch << 4));
    }
#pragma unroll
    for (int i = 0; i < 4; ++i) {
      int r = i * 32 + srow;
      const unsigned char* src = (const unsigned char*)(B + (size_t)(n0 + r) * ldb + k0) + ((sch ^ (r & 7)) << 4);
      load_lds16(src, smem + 16384 + r * 128 + (sch << 4));
    }
    __syncthreads();
#pragma unroll
    for (int kk = 0; kk < 2; ++kk) {
      bf16x8 af[4], bfv[4];
#pragma unroll
      for (int m = 0; m < 4; ++m) {
        int r = wr * 64 + m * 16 + ln15;
        int kc = kk * 4 + lq;
        af[m] = *(const bf16x8*)(smem + r * 128 + ((kc ^ (r & 7)) << 4));
      }
#pragma unroll
      for (int n = 0; n < 4; ++n) {
        int r = wc * 64 + n * 16 + ln15;
        int kc = kk * 4 + lq;
        bfv[n] = *(const bf16x8*)(smem + 16384 + r * 128 + ((kc ^ (r & 7)) << 4));
      }
#pragma unroll
      for (int m = 0; m < 4; ++m)
#pragma unroll
        for (int n = 0; n < 4; ++n)
          acc[m][n] = __builtin_amdgcn_mfma_f32_16x16x32_bf16(af[m], bfv[n], acc[m][n], 0, 0, 0);
    }
    __syncthreads();
  }

#pragma unroll
  for (int m = 0; m < 4; ++m) {
#pragma unroll
    for (int n = 0; n < 4; ++n) {
      int col = n0 + wc * 64 + n * 16 + ln15;
#pragma unroll
      for (int j = 0; j < 4; ++j) {
        int row = m0 + wr * 64 + m * 16 + lq * 4 + j;
        float v = acc[m][n][j];
        size_t idx = (size_t)row * ldc + col;
        if (EPI == 0) {
          ((u16*)Cv)[idx] = f2bf(v);
        } else if (EPI == 3) {
          ((float*)Cv)[idx] = v + aux0[col] + ((const float*)aux1)[idx];
        } else if (EPI == 4) {
          ((u16*)Cv)[idx] = f2bf(gelu_tanh(v + aux0[col]));
        } else if (EPI == 7) {
          ((float*)Cv)[idx] = v + aux0[col] + bf2f(((const u16*)aux1)[idx]);
        }
      }
    }
  }
}

// ---------------------------------------------------------------------------
// fused_kv (proven r6): grid (8 chunks x 64 bh), software-pipelined dbuf.
// ---------------------------------------------------------------------------
__global__ __launch_bounds__(256, 2)
void fused_kv(const u16* __restrict__ qkv, const u16* __restrict__ projT,
              float* __restrict__ kvpart, float* __restrict__ ksumpart)
{
  __shared__ __align__(16) unsigned char ktS[2][8192];
  __shared__ __align__(16) unsigned char vtS[2][8192];
  __shared__ __align__(16) unsigned char kfS[32768];
  const int tid = threadIdx.x;
  const int bh = blockIdx.y, chunk = blockIdx.x;
  const int b = bh >> 4, h = bh & 15;
  const int wid = tid >> 6, lane = tid & 63;
  const int ln15 = lane & 15, lq = lane >> 4;
  const int vN = tid >> 2, vD = (tid & 3) * 16;
  const int vCn = vN >> 3, vWb = (vN & 7) * 2;

  bf16x8 pf[4][2];
#pragma unroll
  for (int m = 0; m < 4; ++m)
#pragma unroll
    for (int kk = 0; kk < 2; ++kk) {
      int f = wid * 64 + m * 16 + ln15;
      pf[m][kk] = *(const bf16x8*)(projT + (size_t)h * 16384 + (size_t)f * 64 + (kk * 4 + lq) * 8);
    }

  float ksum_r = 0.f;
  f32x4 acc2[4][4] = {};
  const int nbase = chunk * 512;

  {
    const u16* kg = qkv + ((size_t)b * 4096 + nbase) * 3072 + 1024 + h * 64;
#pragma unroll
    for (int i = 0; i < 2; ++i) {
      int c = i * 256 + tid; int r = c >> 3, ch = c & 7;
      load_lds16((const unsigned char*)(kg + (size_t)r * 3072) + ((ch ^ (r & 7)) << 4),
                 ktS[0] + r * 128 + ch * 16);
    }
    const u16* vg = qkv + ((size_t)b * 4096 + nbase + vN) * 3072 + 2048 + h * 64 + vD;
    u16x8 va = *(const u16x8*)vg;
    u16x8 vb = *(const u16x8*)(vg + 8);
#pragma unroll
    for (int j = 0; j < 8; ++j) {
      int d = vD + j;
      *(u16*)(vtS[0] + d * 128 + ((vCn ^ (d & 7)) << 4) + vWb) = va[j];
    }
#pragma unroll
    for (int j = 0; j < 8; ++j) {
      int d = vD + 8 + j;
      *(u16*)(vtS[0] + d * 128 + ((vCn ^ (d & 7)) << 4) + vWb) = vb[j];
    }
  }
  __syncthreads();

  for (int t = 0; t < 8; ++t) {
    const int cur = t & 1, nxt = cur ^ 1;
    u16x8 va, vb;
    const bool havenext = (t + 1 < 8);
    if (havenext) {
      int n1 = nbase + (t + 1) * 64;
      const u16* kg = qkv + ((size_t)b * 4096 + n1) * 3072 + 1024 + h * 64;
#pragma unroll
      for (int i = 0; i < 2; ++i) {
        int c = i * 256 + tid; int r = c >> 3, ch = c & 7;
        load_lds16((const unsigned char*)(kg + (size_t)r * 3072) + ((ch ^ (r & 7)) << 4),
                   ktS[nxt] + r * 128 + ch * 16);
      }
      const u16* vg = qkv + ((size_t)b * 4096 + n1 + vN) * 3072 + 2048 + h * 64 + vD;
      va = *(const u16x8*)vg;
      vb = *(const u16x8*)(vg + 8);
    }

    bf16x8 bvk[2][4];
#pragma unroll
    for (int kk = 0; kk < 2; ++kk)
#pragma unroll
      for (int n = 0; n < 4; ++n) {
        int r = n * 16 + ln15, kc = kk * 4 + lq;
        bvk[kk][n] = *(const bf16x8*)(ktS[cur] + r * 128 + ((kc ^ (r & 7)) << 4));
      }
#pragma unroll
    for (int m = 0; m < 4; ++m) {
      f32x4 a1[4] = {};
#pragma unroll
      for (int kk = 0; kk < 2; ++kk)
#pragma unroll
        for (int n = 0; n < 4; ++n)
          a1[n] = __builtin_amdgcn_mfma_f32_16x16x32_bf16(pf[m][kk], bvk[kk][n], a1[n], 0, 0, 0);
#pragma unroll
      for (int n = 0; n < 4; ++n) {
        int nloc = n * 16 + ln15;
        int c = nloc >> 3, wb = (nloc & 7) * 2;
#pragma unroll
        for (int j = 0; j < 4; ++j) {
          int f = wid * 64 + m * 16 + lq * 4 + j;
          float v = a1[n][j];
          float o = v > 0.f ? v + 1.f : __expf(v);
          *(u16*)(kfS + f * 128 + ((c ^ (f & 7)) << 4) + wb) = f2bf(o);
        }
      }
    }
    __syncthreads();

    {
      int f = tid;
      float s = 0.f;
#pragma unroll
      for (int c = 0; c < 8; ++c) {
        u16x8 v = *(const u16x8*)(kfS + f * 128 + ((c ^ (f & 7)) << 4));
#pragma unroll
        for (int j = 0; j < 8; ++j) s += bf2f(v[j]);
      }
      ksum_r += s;
    }
#pragma unroll
    for (int kk = 0; kk < 2; ++kk) {
      int kc = kk * 4 + lq;
      bf16x8 af[4], bv[4];
#pragma unroll
      for (int m = 0; m < 4; ++m) { int r = wid * 64 + m * 16 + ln15; af[m] = *(const bf16x8*)(kfS + r * 128 + ((kc ^ (r & 7)) << 4)); }
#pragma unroll
      for (int n = 0; n < 4; ++n) { int r = n * 16 + ln15; bv[n] = *(const bf16x8*)(vtS[cur] + r * 128 + ((kc ^ (r & 7)) << 4)); }
#pragma unroll
      for (int m = 0; m < 4; ++m)
#pragma unroll
        for (int n = 0; n < 4; ++n)
          acc2[m][n] = __builtin_amdgcn_mfma_f32_16x16x32_bf16(af[m], bv[n], acc2[m][n], 0, 0, 0);
    }
    if (havenext) {
#pragma unroll
      for (int j = 0; j < 8; ++j) {
        int d = vD + j;
        *(u16*)(vtS[nxt] + d * 128 + ((vCn ^ (d & 7)) << 4) + vWb) = va[j];
      }
#pragma unroll
      for (int j = 0; j < 8; ++j) {
        int d = vD + 8 + j;
        *(u16*)(vtS[nxt] + d * 128 + ((vCn ^ (d & 7)) << 4) + vWb) = vb[j];
      }
    }
    __syncthreads();
  }

  const size_t pbase = ((size_t)bh * 8 + chunk) * 16384;
#pragma unroll
  for (int half = 0; half < 2; ++half) {
#pragma unroll
    for (int m = 0; m < 4; ++m)
#pragma unroll
      for (int n2 = 0; n2 < 2; ++n2) {
        int n = half * 2 + n2;
        int dloc = n2 * 16 + ln15;
        int f = wid * 64 + m * 16 + lq * 4;
        *(f32x4*)(kfS + dloc * 1024 + ((f * 4) ^ ((dloc & 7) << 4))) = acc2[m][n];
      }
    __syncthreads();
#pragma unroll
    for (int k = 0; k < 8; ++k) {
      int dloc = k * 4 + wid;
      f32x4 val = *(const f32x4*)(kfS + dloc * 1024 + ((lane * 16) ^ ((dloc & 7) << 4)));
      *(f32x4*)(kvpart + pbase + (size_t)(half * 32 + dloc) * 256 + lane * 4) = val;
    }
    __syncthreads();
  }
  ksumpart[((size_t)bh * 8 + chunk) * 256 + tid] = ksum_r;
}

__global__ __launch_bounds__(256) void kv_finalize(const float* __restrict__ kvpart,
    const float* __restrict__ ksumpart, u16* __restrict__ kvT, float* __restrict__ ksum)
{
  int bx = blockIdx.x, bh = bx >> 2, dq = bx & 3, tid = threadIdx.x;
  const float* base = kvpart + (size_t)bh * 131072;
  u16* out = kvT + (size_t)bh * 16384;
#pragma unroll
  for (int k = 0; k < 16; ++k) {
    int idx = dq * 4096 + k * 256 + tid;
    float s = 0.f;
#pragma unroll
    for (int c = 0; c < 8; ++c) s += base[(size_t)c * 16384 + idx];
    out[idx] = f2bf(s);
  }
  if (dq == 0) {
    float s = 0.f;
#pragma unroll
    for (int c = 0; c < 8; ++c) s += ksumpart[((size_t)bh * 8 + c) * 256 + tid];
    ksum[(size_t)bh * 256 + tid] = s;
  }
}

__global__ __launch_bounds__(256, 3)
void fused_attn(const u16* __restrict__ qkv, const u16* __restrict__ projT,
                const u16* __restrict__ kvT, const float* __restrict__ ksum,
                u16* __restrict__ attnb)
{
  __shared__ __align__(16) unsigned char qtS[8192];
  __shared__ __align__(16) unsigned char qfS[32768];
  __shared__ float zpart[64][4];
  __shared__ float zS[64];
  const int tid = threadIdx.x;
  const int bh = blockIdx.y, nt = blockIdx.x;
  const int b = bh >> 4, h = bh & 15;
  const int wid = tid >> 6, lane = tid & 63;
  const int ln15 = lane & 15, lq = lane >> 4;
  const int n0 = nt * 64;

  bf16x8 pf[4][2];
#pragma unroll
  for (int n = 0; n < 4; ++n)
#pragma unroll
    for (int kk = 0; kk < 2; ++kk) {
      int f = wid * 64 + n * 16 + ln15;
      pf[n][kk] = *(const bf16x8*)(projT + (size_t)h * 16384 + (size_t)f * 64 + (kk * 4 + lq) * 8);
    }

  const u16* qg = qkv + ((size_t)b * 4096 + n0) * 3072 + h * 64;
#pragma unroll
  for (int i = 0; i < 2; ++i) {
    int c = i * 256 + tid; int r = c >> 3, ch = c & 7;
    load_lds16((const unsigned char*)(qg + (size_t)r * 3072) + ((ch ^ (r & 7)) << 4),
               qtS + r * 128 + ch * 16);
  }
  __syncthreads();

#pragma unroll
  for (int m = 0; m < 4; ++m) {
    bf16x8 af[2];
#pragma unroll
    for (int kk = 0; kk < 2; ++kk) {
      int r = m * 16 + ln15, kc = kk * 4 + lq;
      af[kk] = *(const bf16x8*)(qtS + r * 128 + ((kc ^ (r & 7)) << 4));
    }
    f32x4 a1[4] = {};
#pragma unroll
    for (int kk = 0; kk < 2; ++kk)
#pragma unroll
      for (int n = 0; n < 4; ++n)
        a1[n] = __builtin_amdgcn_mfma_f32_16x16x32_bf16(af[kk], pf[n][kk], a1[n], 0, 0, 0);
#pragma unroll
    for (int n = 0; n < 4; ++n) {
      int f = wid * 64 + n * 16 + ln15;
      int c = f >> 3, wb = (f & 7) * 2;
#pragma unroll
      for (int j = 0; j < 4; ++j) {
        int row = m * 16 + lq * 4 + j;
        float v = a1[n][j];
        float o = v > 0.f ? v + 1.f : __expf(v);
        *(u16*)(qfS + row * 512 + ((c ^ (row & 7)) << 4) + wb) = f2bf(o);
      }
    }
  }
  __syncthreads();

  {
    int n = tid & 63, q = tid >> 6;
    const float* kp = ksum + (size_t)bh * 256;
    float s = 0.f;
#pragma unroll
    for (int c = q * 8; c < q * 8 + 8; ++c) {
      u16x8 v = *(const u16x8*)(qfS + n * 512 + ((c ^ (n & 7)) << 4));
#pragma unroll
      for (int j = 0; j < 8; ++j) s += bf2f(v[j]) * kp[c * 8 + j];
    }
    zpart[n][q] = s;
  }
  __syncthreads();
  if (tid < 64) zS[tid] = 1.f / (zpart[tid][0] + zpart[tid][1] + zpart[tid][2] + zpart[tid][3] + 1e-8f);
  __syncthreads();

  f32x4 a2[4] = {};
  const u16* kvg = kvT + (size_t)bh * 16384;
#pragma unroll
  for (int kk = 0; kk < 8; ++kk) {
    int kc = kk * 4 + lq;
    int r = wid * 16 + ln15;
    bf16x8 af = *(const bf16x8*)(qfS + r * 512 + ((kc ^ (r & 7)) << 4));
#pragma unroll
    for (int nf = 0; nf < 4; ++nf) {
      int d = nf * 16 + ln15;
      bf16x8 bv = *(const bf16x8*)(kvg + (size_t)d * 256 + kc * 8);
      a2[nf] = __builtin_amdgcn_mfma_f32_16x16x32_bf16(af, bv, a2[nf], 0, 0, 0);
    }
  }
#pragma unroll
  for (int nf = 0; nf < 4; ++nf)
#pragma unroll
    for (int j = 0; j < 4; ++j) {
      int d = nf * 16 + ln15;
      int n = wid * 16 + lq * 4 + j;
      float v = a2[nf][j] * zS[n];
      attnb[((size_t)b * 4096 + n0 + n) * 1024 + h * 64 + d] = f2bf(v);
    }
}

__global__ __launch_bounds__(256) void cast_kernel(const float* __restrict__ in, u16* __restrict__ out, int n4)
{
  int i = blockIdx.x * 256 + threadIdx.x;
  if (i >= n4) return;
  float4 v = ((const float4*)in)[i];
  u16x4 o = { f2bf(v.x), f2bf(v.y), f2bf(v.z), f2bf(v.w) };
  ((u16x4*)out)[i] = o;
}

__global__ __launch_bounds__(256) void projt_kernel(const float* __restrict__ proj, u16* __restrict__ out)
{
  int i = blockIdx.x * 256 + threadIdx.x;
  int d = i & 63, f = (i >> 6) & 255, h = i >> 14;
  out[i] = f2bf(proj[((size_t)h * 64 + d) * 256 + f]);
}

// LayerNorm over 1024 f32; outF (f32) and outB (bf16) each optional.
__global__ __launch_bounds__(256) void ln_kernel(const float* __restrict__ in, const float* __restrict__ gamma,
                                                 const float* __restrict__ beta, float* __restrict__ outF,
                                                 u16* __restrict__ outB)
{
  int row = blockIdx.x, tid = threadIdx.x;
  float4 v = ((const float4*)(in + (size_t)row * 1024))[tid];
  float s = v.x + v.y + v.z + v.w;
  float q = v.x * v.x + v.y * v.y + v.z * v.z + v.w * v.w;
  for (int off = 32; off; off >>= 1) { s += __shfl_down(s, off); q += __shfl_down(q, off); }
  __shared__ float rs[4], rq[4];
  int wid = tid >> 6, lane = tid & 63;
  if (!lane) { rs[wid] = s; rq[wid] = q; }
  __syncthreads();
  s = rs[0] + rs[1] + rs[2] + rs[3];
  q = rq[0] + rq[1] + rq[2] + rq[3];
  float mu = s * (1.f / 1024.f);
  float rstd = rsqrtf(q * (1.f / 1024.f) - mu * mu + 1e-5f);
  float4 g = ((const float4*)gamma)[tid];
  float4 bb = ((const float4*)beta)[tid];
  float4 o;
  o.x = (v.x - mu) * rstd * g.x + bb.x;
  o.y = (v.y - mu) * rstd * g.y + bb.y;
  o.z = (v.z - mu) * rstd * g.z + bb.z;
  o.w = (v.w - mu) * rstd * g.w + bb.w;
  if (outF) ((float4*)(outF + (size_t)row * 1024))[tid] = o;
  if (outB) {
    u16x4 ob = { f2bf(o.x), f2bf(o.y), f2bf(o.z), f2bf(o.w) };
    ((u16x4*)(outB + (size_t)row * 1024))[tid] = ob;
  }
}

// ---------------------------------------------------------------------------
// Workspace (205 MB). d_out doubles as scratch:
//   phase A: xb (bf16 x) in d_out[0..33.5MB)
//   phase B: kvpart f32 in d_out (33.5MB)
//   phase C: outproj f32 (full overwrite) -> LN -> final
// hfull (134MB) overlays dead qkvb+attnb during MLP.
// ---------------------------------------------------------------------------
#define O_WQKVB   0L
#define O_WOUTB   6291456L
#define O_W1B     8388608L
#define O_W2B     16777216L
#define O_PROJT   25165824L
#define O_KSUM    25690112L
#define O_KSP     26804224L
#define O_KVB     27852800L
#define O_QFG     37289984L
#define O_QKVB    70844416L
#define O_ATTNB   171507712L
#define WS_NEED   205062144L

extern "C" void kernel_launch(void* const* d_in, const int* in_sizes, int n_in,
                              void* d_out, int out_size, void* d_ws, size_t ws_size,
                              hipStream_t stream)
{
  if (ws_size < (size_t)WS_NEED) return;

  const float* x     = (const float*)d_in[0];
  const float* proj  = (const float*)d_in[1];
  const float* wqkv  = (const float*)d_in[2];
  const float* wout  = (const float*)d_in[3];
  const float* bout  = (const float*)d_in[4];
  const float* gamma = (const float*)d_in[5];
  const float* beta  = (const float*)d_in[6];
  const float* w1    = (const float*)d_in[7];
  const float* b1    = (const float*)d_in[8];
  const float* w2    = (const float*)d_in[9];
  const float* b2    = (const float*)d_in[10];
  float* outp = (float*)d_out;
  char* ws = (char*)d_ws;

  u16* wqkvb  = (u16*)(ws + O_WQKVB);
  u16* woutb  = (u16*)(ws + O_WOUTB);
  u16* w1b    = (u16*)(ws + O_W1B);
  u16* w2b    = (u16*)(ws + O_W2B);
  u16* projTb = (u16*)(ws + O_PROJT);
  float* ksumf= (float*)(ws + O_KSUM);
  float* ksp  = (float*)(ws + O_KSP);
  u16* kvTb   = (u16*)(ws + O_KVB);
  u16* qkvb   = (u16*)(ws + O_QKVB);
  u16* attnb  = (u16*)(ws + O_ATTNB);
  u16* x1b    = (u16*)(ws + O_QFG);
  u16* hfull  = (u16*)(ws + O_QKVB);   // 134MB, overlays dead qkvb+attnb

  u16* xbD   = (u16*)d_out;
  float* kvp = (float*)d_out;

  cast_kernel<<<16384, 256, 0, stream>>>(x, xbD, 4194304);
  cast_kernel<<<3072, 256, 0, stream>>>(wqkv, wqkvb, 786432);
  cast_kernel<<<1024, 256, 0, stream>>>(wout, woutb, 262144);
  cast_kernel<<<4096, 256, 0, stream>>>(w1, w1b, 1048576);
  cast_kernel<<<4096, 256, 0, stream>>>(w2, w2b, 1048576);
  projt_kernel<<<1024, 256, 0, stream>>>(proj, projTb);

  // qkv = x @ w_qkv^T : M=16384, N=3072, K=1024   (928 TF proven config)
  gemm_nt<0><<<dim3(24, 128), 256, 0, stream>>>(xbD, wqkvb, qkvb, nullptr, nullptr,
      16384, 3072, 1024, 1024, 1024, 3072);

  fused_kv<<<dim3(8, 64), 256, 0, stream>>>(qkvb, projTb, kvp, ksp);
  kv_finalize<<<256, 256, 0, stream>>>(kvp, ksp, kvTb, ksumf);
  fused_attn<<<dim3(64, 64), 256, 0, stream>>>(qkvb, projTb, kvTb, ksumf, attnb);

  // t = x + attn @ w_out^T + b_out : f32 -> d_out
  gemm_nt<3><<<dim3(8, 128), 256, 0, stream>>>(attnb, woutb, outp, bout, x,
      16384, 1024, 1024, 1024, 1024, 1024);

  // x1 = LN(t): bf16 only (residual + MLP input both read bf16)
  ln_kernel<<<16384, 256, 0, stream>>>(outp, gamma, beta, nullptr, x1b);

  // h = gelu_tanh(x1 @ w1^T + b1) : M=16384, N=4096, K=1024
  gemm_nt<4><<<dim3(32, 128), 256, 0, stream>>>(x1b, w1b, hfull, b1, nullptr,
      16384, 4096, 1024, 1024, 1024, 4096);

  // y = x1(bf16) + h @ w2^T + b2 : f32 -> d_out (full overwrite)
  gemm_nt<7><<<dim3(8, 128), 256, 0, stream>>>(hfull, w2b, outp, b2, x1b,
      16384, 1024, 4096, 4096, 4096, 1024);

  ln_kernel<<<16384, 256, 0, stream>>>(outp, gamma, beta, outp, nullptr);
}

// Round 10
// 656.759 us; speedup vs baseline: 1.7131x; 1.0609x over previous
//
#include <hip/hip_runtime.h>
#include <math.h>

typedef unsigned short u16;
typedef __bf16 bf16x8 __attribute__((ext_vector_type(8)));
typedef float f32x4 __attribute__((ext_vector_type(4)));
typedef unsigned short u16x4 __attribute__((ext_vector_type(4)));
typedef unsigned short u16x8 __attribute__((ext_vector_type(8)));

#define DEV static __device__ __forceinline__

DEV float bf2f(u16 u) { union { unsigned int i; float f; } x; x.i = ((unsigned int)u) << 16; return x.f; }
DEV u16 f2bf(float f) { union { float f; unsigned int i; } x; x.f = f; unsigned int r = x.i + 0x7fffu + ((x.i >> 16) & 1u); return (u16)(r >> 16); }

DEV void load_lds16(const void* g, void* l) {
  __builtin_amdgcn_global_load_lds((__attribute__((address_space(1))) void*)g,
                                   (__attribute__((address_space(3))) void*)l, 16, 0, 0);
}

// sigmoid-form tanh-GELU; |err vs erf-gelu| <= ~3e-3
DEV float gelu_tanh(float g) {
  float t = 0.7978845608f * g * (1.f + 0.044715f * g * g);
  return g / (1.f + __expf(-2.f * t));
}

// ---------------------------------------------------------------------------
// Generic NT GEMM (proven): 128x128 tile, BK=64, 4 waves, MFMA 16x16x32,
// XOR swizzle both-sides. Raster: XCD chunk (T1) + 8x8 sub-block order so the
// ~64 concurrent blocks/XCD touch A 2MB + B 2MB (fits 4MB L2); falls back to
// linear T1 when grid shape doesn't divide.
// EPI: 0 bf16 | 3 f32 v+aux0[col]+f32aux1[idx] | 4 bias+gelu(tanh) bf16 |
//      7 f32 v+aux0[col]+bf16aux1[idx]
// ---------------------------------------------------------------------------
template<int EPI>
__global__ __launch_bounds__(256, 2)
void gemm_nt(const u16* __restrict__ A, const u16* __restrict__ B, void* __restrict__ Cv,
             const float* __restrict__ aux0, const void* __restrict__ aux1,
             int M, int N, int K, int lda, int ldb, int ldc)
{
  __shared__ __align__(16) unsigned char smem[32768];
  const int tid = threadIdx.x;
  int bx = blockIdx.x, by = blockIdx.y;
  {
    const int GX = gridDim.x;
    const int nwg = GX * gridDim.y;
    if ((nwg & 7) == 0) {
      const int wg = by * GX + bx;
      const int cpx = nwg >> 3;
      const int xcd = wg & 7, s = wg >> 3;
      const int rows = cpx / GX;
      if ((GX & 7) == 0 && cpx == rows * GX && (rows & 7) == 0) {
        const int SC = GX >> 3;
        const int q = s >> 6, r = (s >> 3) & 7, c = s & 7;
        by = xcd * rows + (q / SC) * 8 + r;
        bx = (q % SC) * 8 + c;
      } else {
        const int swz = xcd * cpx + s;
        bx = swz % GX; by = swz / GX;
      }
    }
  }
  const int m0 = by * 128, n0 = bx * 128;
  const int wid = tid >> 6, lane = tid & 63;
  const int wr = wid >> 1, wc = wid & 1;
  const int ln15 = lane & 15, lq = lane >> 4;
  const int srow = tid >> 3, sch = tid & 7;

  f32x4 acc[4][4] = {};

  for (int k0 = 0; k0 < K; k0 += 64) {
#pragma unroll
    for (int i = 0; i < 4; ++i) {
      int r = i * 32 + srow;
      const unsigned char* src = (const unsigned char*)(A + (size_t)(m0 + r) * lda + k0) + ((sch ^ (r & 7)) << 4);
      load_lds16(src, smem + r * 128 + (sch << 4));
    }
#pragma unroll
    for (int i = 0; i < 4; ++i) {
      int r = i * 32 + srow;
      const unsigned char* src = (const unsigned char*)(B + (size_t)(n0 + r) * ldb + k0) + ((sch ^ (r & 7)) << 4);
      load_lds16(src, smem + 16384 + r * 128 + (sch << 4));
    }
    __syncthreads();
#pragma unroll
    for (int kk = 0; kk < 2; ++kk) {
      bf16x8 af[4], bfv[4];
#pragma unroll
      for (int m = 0; m < 4; ++m) {
        int r = wr * 64 + m * 16 + ln15;
        int kc = kk * 4 + lq;
        af[m] = *(const bf16x8*)(smem + r * 128 + ((kc ^ (r & 7)) << 4));
      }
#pragma unroll
      for (int n = 0; n < 4; ++n) {
        int r = wc * 64 + n * 16 + ln15;
        int kc = kk * 4 + lq;
        bfv[n] = *(const bf16x8*)(smem + 16384 + r * 128 + ((kc ^ (r & 7)) << 4));
      }
#pragma unroll
      for (int m = 0; m < 4; ++m)
#pragma unroll
        for (int n = 0; n < 4; ++n)
          acc[m][n] = __builtin_amdgcn_mfma_f32_16x16x32_bf16(af[m], bfv[n], acc[m][n], 0, 0, 0);
    }
    __syncthreads();
  }

#pragma unroll
  for (int m = 0; m < 4; ++m) {
#pragma unroll
    for (int n = 0; n < 4; ++n) {
      int col = n0 + wc * 64 + n * 16 + ln15;
#pragma unroll
      for (int j = 0; j < 4; ++j) {
        int row = m0 + wr * 64 + m * 16 + lq * 4 + j;
        float v = acc[m][n][j];
        size_t idx = (size_t)row * ldc + col;
        if (EPI == 0) {
          ((u16*)Cv)[idx] = f2bf(v);
        } else if (EPI == 3) {
          ((float*)Cv)[idx] = v + aux0[col] + ((const float*)aux1)[idx];
        } else if (EPI == 4) {
          ((u16*)Cv)[idx] = f2bf(gelu_tanh(v + aux0[col]));
        } else if (EPI == 7) {
          ((float*)Cv)[idx] = v + aux0[col] + bf2f(((const u16*)aux1)[idx]);
        }
      }
    }
  }
}

// ---------------------------------------------------------------------------
// fused_kv (proven r6): grid (8 chunks x 64 bh), software-pipelined dbuf.
// ---------------------------------------------------------------------------
__global__ __launch_bounds__(256, 2)
void fused_kv(const u16* __restrict__ qkv, const u16* __restrict__ projT,
              float* __restrict__ kvpart, float* __restrict__ ksumpart)
{
  __shared__ __align__(16) unsigned char ktS[2][8192];
  __shared__ __align__(16) unsigned char vtS[2][8192];
  __shared__ __align__(16) unsigned char kfS[32768];
  const int tid = threadIdx.x;
  const int bh = blockIdx.y, chunk = blockIdx.x;
  const int b = bh >> 4, h = bh & 15;
  const int wid = tid >> 6, lane = tid & 63;
  const int ln15 = lane & 15, lq = lane >> 4;
  const int vN = tid >> 2, vD = (tid & 3) * 16;
  const int vCn = vN >> 3, vWb = (vN & 7) * 2;

  bf16x8 pf[4][2];
#pragma unroll
  for (int m = 0; m < 4; ++m)
#pragma unroll
    for (int kk = 0; kk < 2; ++kk) {
      int f = wid * 64 + m * 16 + ln15;
      pf[m][kk] = *(const bf16x8*)(projT + (size_t)h * 16384 + (size_t)f * 64 + (kk * 4 + lq) * 8);
    }

  float ksum_r = 0.f;
  f32x4 acc2[4][4] = {};
  const int nbase = chunk * 512;

  {
    const u16* kg = qkv + ((size_t)b * 4096 + nbase) * 3072 + 1024 + h * 64;
#pragma unroll
    for (int i = 0; i < 2; ++i) {
      int c = i * 256 + tid; int r = c >> 3, ch = c & 7;
      load_lds16((const unsigned char*)(kg + (size_t)r * 3072) + ((ch ^ (r & 7)) << 4),
                 ktS[0] + r * 128 + ch * 16);
    }
    const u16* vg = qkv + ((size_t)b * 4096 + nbase + vN) * 3072 + 2048 + h * 64 + vD;
    u16x8 va = *(const u16x8*)vg;
    u16x8 vb = *(const u16x8*)(vg + 8);
#pragma unroll
    for (int j = 0; j < 8; ++j) {
      int d = vD + j;
      *(u16*)(vtS[0] + d * 128 + ((vCn ^ (d & 7)) << 4) + vWb) = va[j];
    }
#pragma unroll
    for (int j = 0; j < 8; ++j) {
      int d = vD + 8 + j;
      *(u16*)(vtS[0] + d * 128 + ((vCn ^ (d & 7)) << 4) + vWb) = vb[j];
    }
  }
  __syncthreads();

  for (int t = 0; t < 8; ++t) {
    const int cur = t & 1, nxt = cur ^ 1;
    u16x8 va, vb;
    const bool havenext = (t + 1 < 8);
    if (havenext) {
      int n1 = nbase + (t + 1) * 64;
      const u16* kg = qkv + ((size_t)b * 4096 + n1) * 3072 + 1024 + h * 64;
#pragma unroll
      for (int i = 0; i < 2; ++i) {
        int c = i * 256 + tid; int r = c >> 3, ch = c & 7;
        load_lds16((const unsigned char*)(kg + (size_t)r * 3072) + ((ch ^ (r & 7)) << 4),
                   ktS[nxt] + r * 128 + ch * 16);
      }
      const u16* vg = qkv + ((size_t)b * 4096 + n1 + vN) * 3072 + 2048 + h * 64 + vD;
      va = *(const u16x8*)vg;
      vb = *(const u16x8*)(vg + 8);
    }

    bf16x8 bvk[2][4];
#pragma unroll
    for (int kk = 0; kk < 2; ++kk)
#pragma unroll
      for (int n = 0; n < 4; ++n) {
        int r = n * 16 + ln15, kc = kk * 4 + lq;
        bvk[kk][n] = *(const bf16x8*)(ktS[cur] + r * 128 + ((kc ^ (r & 7)) << 4));
      }
#pragma unroll
    for (int m = 0; m < 4; ++m) {
      f32x4 a1[4] = {};
#pragma unroll
      for (int kk = 0; kk < 2; ++kk)
#pragma unroll
        for (int n = 0; n < 4; ++n)
          a1[n] = __builtin_amdgcn_mfma_f32_16x16x32_bf16(pf[m][kk], bvk[kk][n], a1[n], 0, 0, 0);
#pragma unroll
      for (int n = 0; n < 4; ++n) {
        int nloc = n * 16 + ln15;
        int c = nloc >> 3, wb = (nloc & 7) * 2;
#pragma unroll
        for (int j = 0; j < 4; ++j) {
          int f = wid * 64 + m * 16 + lq * 4 + j;
          float v = a1[n][j];
          float o = v > 0.f ? v + 1.f : __expf(v);
          *(u16*)(kfS + f * 128 + ((c ^ (f & 7)) << 4) + wb) = f2bf(o);
        }
      }
    }
    __syncthreads();

    {
      int f = tid;
      float s = 0.f;
#pragma unroll
      for (int c = 0; c < 8; ++c) {
        u16x8 v = *(const u16x8*)(kfS + f * 128 + ((c ^ (f & 7)) << 4));
#pragma unroll
        for (int j = 0; j < 8; ++j) s += bf2f(v[j]);
      }
      ksum_r += s;
    }
#pragma unroll
    for (int kk = 0; kk < 2; ++kk) {
      int kc = kk * 4 + lq;
      bf16x8 af[4], bv[4];
#pragma unroll
      for (int m = 0; m < 4; ++m) { int r = wid * 64 + m * 16 + ln15; af[m] = *(const bf16x8*)(kfS + r * 128 + ((kc ^ (r & 7)) << 4)); }
#pragma unroll
      for (int n = 0; n < 4; ++n) { int r = n * 16 + ln15; bv[n] = *(const bf16x8*)(vtS[cur] + r * 128 + ((kc ^ (r & 7)) << 4)); }
#pragma unroll
      for (int m = 0; m < 4; ++m)
#pragma unroll
        for (int n = 0; n < 4; ++n)
          acc2[m][n] = __builtin_amdgcn_mfma_f32_16x16x32_bf16(af[m], bv[n], acc2[m][n], 0, 0, 0);
    }
    if (havenext) {
#pragma unroll
      for (int j = 0; j < 8; ++j) {
        int d = vD + j;
        *(u16*)(vtS[nxt] + d * 128 + ((vCn ^ (d & 7)) << 4) + vWb) = va[j];
      }
#pragma unroll
      for (int j = 0; j < 8; ++j) {
        int d = vD + 8 + j;
        *(u16*)(vtS[nxt] + d * 128 + ((vCn ^ (d & 7)) << 4) + vWb) = vb[j];
      }
    }
    __syncthreads();
  }

  const size_t pbase = ((size_t)bh * 8 + chunk) * 16384;
#pragma unroll
  for (int half = 0; half < 2; ++half) {
#pragma unroll
    for (int m = 0; m < 4; ++m)
#pragma unroll
      for (int n2 = 0; n2 < 2; ++n2) {
        int n = half * 2 + n2;
        int dloc = n2 * 16 + ln15;
        int f = wid * 64 + m * 16 + lq * 4;
        *(f32x4*)(kfS + dloc * 1024 + ((f * 4) ^ ((dloc & 7) << 4))) = acc2[m][n];
      }
    __syncthreads();
#pragma unroll
    for (int k = 0; k < 8; ++k) {
      int dloc = k * 4 + wid;
      f32x4 val = *(const f32x4*)(kfS + dloc * 1024 + ((lane * 16) ^ ((dloc & 7) << 4)));
      *(f32x4*)(kvpart + pbase + (size_t)(half * 32 + dloc) * 256 + lane * 4) = val;
    }
    __syncthreads();
  }
  ksumpart[((size_t)bh * 8 + chunk) * 256 + tid] = ksum_r;
}

__global__ __launch_bounds__(256) void kv_finalize(const float* __restrict__ kvpart,
    const float* __restrict__ ksumpart, u16* __restrict__ kvT, float* __restrict__ ksum)
{
  int bx = blockIdx.x, bh = bx >> 2, dq = bx & 3, tid = threadIdx.x;
  const float* base = kvpart + (size_t)bh * 131072;
  u16* out = kvT + (size_t)bh * 16384;
#pragma unroll
  for (int k = 0; k < 16; ++k) {
    int idx = dq * 4096 + k * 256 + tid;
    float s = 0.f;
#pragma unroll
    for (int c = 0; c < 8; ++c) s += base[(size_t)c * 16384 + idx];
    out[idx] = f2bf(s);
  }
  if (dq == 0) {
    float s = 0.f;
#pragma unroll
    for (int c = 0; c < 8; ++c) s += ksumpart[((size_t)bh * 8 + c) * 256 + tid];
    ksum[(size_t)bh * 256 + tid] = s;
  }
}

__global__ __launch_bounds__(256, 3)
void fused_attn(const u16* __restrict__ qkv, const u16* __restrict__ projT,
                const u16* __restrict__ kvT, const float* __restrict__ ksum,
                u16* __restrict__ attnb)
{
  __shared__ __align__(16) unsigned char qtS[8192];
  __shared__ __align__(16) unsigned char qfS[32768];
  __shared__ float zpart[64][4];
  __shared__ float zS[64];
  const int tid = threadIdx.x;
  const int bh = blockIdx.y, nt = blockIdx.x;
  const int b = bh >> 4, h = bh & 15;
  const int wid = tid >> 6, lane = tid & 63;
  const int ln15 = lane & 15, lq = lane >> 4;
  const int n0 = nt * 64;

  bf16x8 pf[4][2];
#pragma unroll
  for (int n = 0; n < 4; ++n)
#pragma unroll
    for (int kk = 0; kk < 2; ++kk) {
      int f = wid * 64 + n * 16 + ln15;
      pf[n][kk] = *(const bf16x8*)(projT + (size_t)h * 16384 + (size_t)f * 64 + (kk * 4 + lq) * 8);
    }

  const u16* qg = qkv + ((size_t)b * 4096 + n0) * 3072 + h * 64;
#pragma unroll
  for (int i = 0; i < 2; ++i) {
    int c = i * 256 + tid; int r = c >> 3, ch = c & 7;
    load_lds16((const unsigned char*)(qg + (size_t)r * 3072) + ((ch ^ (r & 7)) << 4),
               qtS + r * 128 + ch * 16);
  }
  __syncthreads();

#pragma unroll
  for (int m = 0; m < 4; ++m) {
    bf16x8 af[2];
#pragma unroll
    for (int kk = 0; kk < 2; ++kk) {
      int r = m * 16 + ln15, kc = kk * 4 + lq;
      af[kk] = *(const bf16x8*)(qtS + r * 128 + ((kc ^ (r & 7)) << 4));
    }
    f32x4 a1[4] = {};
#pragma unroll
    for (int kk = 0; kk < 2; ++kk)
#pragma unroll
      for (int n = 0; n < 4; ++n)
        a1[n] = __builtin_amdgcn_mfma_f32_16x16x32_bf16(af[kk], pf[n][kk], a1[n], 0, 0, 0);
#pragma unroll
    for (int n = 0; n < 4; ++n) {
      int f = wid * 64 + n * 16 + ln15;
      int c = f >> 3, wb = (f & 7) * 2;
#pragma unroll
      for (int j = 0; j < 4; ++j) {
        int row = m * 16 + lq * 4 + j;
        float v = a1[n][j];
        float o = v > 0.f ? v + 1.f : __expf(v);
        *(u16*)(qfS + row * 512 + ((c ^ (row & 7)) << 4) + wb) = f2bf(o);
      }
    }
  }
  __syncthreads();

  {
    int n = tid & 63, q = tid >> 6;
    const float* kp = ksum + (size_t)bh * 256;
    float s = 0.f;
#pragma unroll
    for (int c = q * 8; c < q * 8 + 8; ++c) {
      u16x8 v = *(const u16x8*)(qfS + n * 512 + ((c ^ (n & 7)) << 4));
#pragma unroll
      for (int j = 0; j < 8; ++j) s += bf2f(v[j]) * kp[c * 8 + j];
    }
    zpart[n][q] = s;
  }
  __syncthreads();
  if (tid < 64) zS[tid] = 1.f / (zpart[tid][0] + zpart[tid][1] + zpart[tid][2] + zpart[tid][3] + 1e-8f);
  __syncthreads();

  f32x4 a2[4] = {};
  const u16* kvg = kvT + (size_t)bh * 16384;
#pragma unroll
  for (int kk = 0; kk < 8; ++kk) {
    int kc = kk * 4 + lq;
    int r = wid * 16 + ln15;
    bf16x8 af = *(const bf16x8*)(qfS + r * 512 + ((kc ^ (r & 7)) << 4));
#pragma unroll
    for (int nf = 0; nf < 4; ++nf) {
      int d = nf * 16 + ln15;
      bf16x8 bv = *(const bf16x8*)(kvg + (size_t)d * 256 + kc * 8);
      a2[nf] = __builtin_amdgcn_mfma_f32_16x16x32_bf16(af, bv, a2[nf], 0, 0, 0);
    }
  }
#pragma unroll
  for (int nf = 0; nf < 4; ++nf)
#pragma unroll
    for (int j = 0; j < 4; ++j) {
      int d = nf * 16 + ln15;
      int n = wid * 16 + lq * 4 + j;
      float v = a2[nf][j] * zS[n];
      attnb[((size_t)b * 4096 + n0 + n) * 1024 + h * 64 + d] = f2bf(v);
    }
}

// x cast (big, separate)
__global__ __launch_bounds__(256) void cast_kernel(const float* __restrict__ in, u16* __restrict__ out, int n4)
{
  int i = blockIdx.x * 256 + threadIdx.x;
  if (i >= n4) return;
  float4 v = ((const float4*)in)[i];
  u16x4 o = { f2bf(v.x), f2bf(v.y), f2bf(v.z), f2bf(v.w) };
  ((u16x4*)out)[i] = o;
}

// all 4 weight casts in one launch: grid 12288 blocks
__global__ __launch_bounds__(256) void castw_kernel(const float* __restrict__ wqkv, const float* __restrict__ wout,
                                                    const float* __restrict__ w1, const float* __restrict__ w2,
                                                    u16* __restrict__ owqkv, u16* __restrict__ owout,
                                                    u16* __restrict__ ow1, u16* __restrict__ ow2)
{
  int bid = blockIdx.x;
  const float* src; u16* dst; int base;
  if (bid < 3072)      { src = wqkv; dst = owqkv; base = bid; }
  else if (bid < 4096) { src = wout; dst = owout; base = bid - 3072; }
  else if (bid < 8192) { src = w1;   dst = ow1;   base = bid - 4096; }
  else                 { src = w2;   dst = ow2;   base = bid - 8192; }
  int i = base * 256 + threadIdx.x;
  float4 v = ((const float4*)src)[i];
  u16x4 o = { f2bf(v.x), f2bf(v.y), f2bf(v.z), f2bf(v.w) };
  ((u16x4*)dst)[i] = o;
}

__global__ __launch_bounds__(256) void projt_kernel(const float* __restrict__ proj, u16* __restrict__ out)
{
  int i = blockIdx.x * 256 + threadIdx.x;
  int d = i & 63, f = (i >> 6) & 255, h = i >> 14;
  out[i] = f2bf(proj[((size_t)h * 64 + d) * 256 + f]);
}

// LayerNorm over 1024 f32; outF (f32) and outB (bf16) each optional.
__global__ __launch_bounds__(256) void ln_kernel(const float* __restrict__ in, const float* __restrict__ gamma,
                                                 const float* __restrict__ beta, float* __restrict__ outF,
                                                 u16* __restrict__ outB)
{
  int row = blockIdx.x, tid = threadIdx.x;
  float4 v = ((const float4*)(in + (size_t)row * 1024))[tid];
  float s = v.x + v.y + v.z + v.w;
  float q = v.x * v.x + v.y * v.y + v.z * v.z + v.w * v.w;
  for (int off = 32; off; off >>= 1) { s += __shfl_down(s, off); q += __shfl_down(q, off); }
  __shared__ float rs[4], rq[4];
  int wid = tid >> 6, lane = tid & 63;
  if (!lane) { rs[wid] = s; rq[wid] = q; }
  __syncthreads();
  s = rs[0] + rs[1] + rs[2] + rs[3];
  q = rq[0] + rq[1] + rq[2] + rq[3];
  float mu = s * (1.f / 1024.f);
  float rstd = rsqrtf(q * (1.f / 1024.f) - mu * mu + 1e-5f);
  float4 g = ((const float4*)gamma)[tid];
  float4 bb = ((const float4*)beta)[tid];
  float4 o;
  o.x = (v.x - mu) * rstd * g.x + bb.x;
  o.y = (v.y - mu) * rstd * g.y + bb.y;
  o.z = (v.z - mu) * rstd * g.z + bb.z;
  o.w = (v.w - mu) * rstd * g.w + bb.w;
  if (outF) ((float4*)(outF + (size_t)row * 1024))[tid] = o;
  if (outB) {
    u16x4 ob = { f2bf(o.x), f2bf(o.y), f2bf(o.z), f2bf(o.w) };
    ((u16x4*)(outB + (size_t)row * 1024))[tid] = ob;
  }
}

// ---------------------------------------------------------------------------
// Buffer plan (ws 205 MB + d_out 67 MB as scratch):
//   d_out: xb (bf16 x) [0..33.5MB) — alive until outproj reads it as residual;
//          then w2 overwrites d_out with final f32.
//   ws O_QFG  (33.5MB): kvpart f32 (fused_kv) -> then x1b (bf16, LN1 out)
//   ws O_QKVB (134MB) : qkvb -> then t (outproj f32, 67MB) -> then hfull
//   ws O_ATTNB (33.5MB): attnb
// ---------------------------------------------------------------------------
#define O_WQKVB   0L
#define O_WOUTB   6291456L
#define O_W1B     8388608L
#define O_W2B     16777216L
#define O_PROJT   25165824L
#define O_KSUM    25690112L
#define O_KSP     26804224L
#define O_KVB     27852800L
#define O_QFG     37289984L
#define O_QKVB    70844416L
#define O_ATTNB   171507712L
#define WS_NEED   205062144L

extern "C" void kernel_launch(void* const* d_in, const int* in_sizes, int n_in,
                              void* d_out, int out_size, void* d_ws, size_t ws_size,
                              hipStream_t stream)
{
  if (ws_size < (size_t)WS_NEED) return;

  const float* x     = (const float*)d_in[0];
  const float* proj  = (const float*)d_in[1];
  const float* wqkv  = (const float*)d_in[2];
  const float* wout  = (const float*)d_in[3];
  const float* bout  = (const float*)d_in[4];
  const float* gamma = (const float*)d_in[5];
  const float* beta  = (const float*)d_in[6];
  const float* w1    = (const float*)d_in[7];
  const float* b1    = (const float*)d_in[8];
  const float* w2    = (const float*)d_in[9];
  const float* b2    = (const float*)d_in[10];
  float* outp = (float*)d_out;
  char* ws = (char*)d_ws;

  u16* wqkvb  = (u16*)(ws + O_WQKVB);
  u16* woutb  = (u16*)(ws + O_WOUTB);
  u16* w1b    = (u16*)(ws + O_W1B);
  u16* w2b    = (u16*)(ws + O_W2B);
  u16* projTb = (u16*)(ws + O_PROJT);
  float* ksumf= (float*)(ws + O_KSUM);
  float* ksp  = (float*)(ws + O_KSP);
  u16* kvTb   = (u16*)(ws + O_KVB);
  float* kvp  = (float*)(ws + O_QFG);     // 33.5MB, dead after kv_finalize
  u16* x1b    = (u16*)(ws + O_QFG);       // reuses kvp region
  u16* qkvb   = (u16*)(ws + O_QKVB);      // dead after fused_attn
  float* tf   = (float*)(ws + O_QKVB);    // outproj f32 out (67MB), dead after LN1
  u16* hfull  = (u16*)(ws + O_QKVB);      // 134MB, overlays tf after LN1
  u16* attnb  = (u16*)(ws + O_ATTNB);

  u16* xbD = (u16*)d_out;                 // bf16 x, alive until outproj

  cast_kernel<<<16384, 256, 0, stream>>>(x, xbD, 4194304);
  castw_kernel<<<12288, 256, 0, stream>>>(wqkv, wout, w1, w2, wqkvb, woutb, w1b, w2b);
  projt_kernel<<<1024, 256, 0, stream>>>(proj, projTb);

  // qkv = x @ w_qkv^T : M=16384, N=3072, K=1024
  gemm_nt<0><<<dim3(24, 128), 256, 0, stream>>>(xbD, wqkvb, qkvb, nullptr, nullptr,
      16384, 3072, 1024, 1024, 1024, 3072);

  fused_kv<<<dim3(8, 64), 256, 0, stream>>>(qkvb, projTb, kvp, ksp);
  kv_finalize<<<256, 256, 0, stream>>>(kvp, ksp, kvTb, ksumf);
  fused_attn<<<dim3(64, 64), 256, 0, stream>>>(qkvb, projTb, kvTb, ksumf, attnb);

  // t = xb(bf16) + attn @ w_out^T + b_out : f32 -> tf (ws; qkvb dead)
  gemm_nt<7><<<dim3(8, 128), 256, 0, stream>>>(attnb, woutb, tf, bout, xbD,
      16384, 1024, 1024, 1024, 1024, 1024);

  // x1 = LN(t): bf16 only
  ln_kernel<<<16384, 256, 0, stream>>>(tf, gamma, beta, nullptr, x1b);

  // h = gelu_tanh(x1 @ w1^T + b1) : M=16384, N=4096, K=1024 (hfull overlays tf)
  gemm_nt<4><<<dim3(32, 128), 256, 0, stream>>>(x1b, w1b, hfull, b1, nullptr,
      16384, 4096, 1024, 1024, 1024, 4096);

  // y = x1(bf16) + h @ w2^T + b2 : f32 -> d_out (xb dead, full overwrite)
  gemm_nt<7><<<dim3(8, 128), 256, 0, stream>>>(hfull, w2b, outp, b2, x1b,
      16384, 1024, 4096, 4096, 4096, 1024);

  ln_kernel<<<16384, 256, 0, stream>>>(outp, gamma, beta, outp, nullptr);
}